// Round 6
// baseline (170.419 us; speedup 1.0000x reference)
//
#include <hip/hip_runtime.h>

#define HN 20
#define G4 80
#define EPSC 1e-5f
#define L2E 1.4426950408889634f

typedef float v2f __attribute__((ext_vector_type(2)));
typedef float v4f __attribute__((ext_vector_type(4)));

#if __has_builtin(__builtin_amdgcn_exp2f)
#define EXP2(x) __builtin_amdgcn_exp2f(x)
#else
#define EXP2(x) __expf((x) * 0.6931471805599453f)
#endif
#define RCP(x) __builtin_amdgcn_rcpf(x)
#define RSQ(x) __builtin_amdgcn_rsqf(x)
// z pre-scaled by -L2E  -> SIG2(z) = sigmoid(z_orig)
#define SIG2(z) RCP(1.f + EXP2(z))
// z pre-scaled by +2*L2E -> TANH2(z) = tanh(z_orig)
#define TANH2(z) fmaf(-2.f, RCP(1.f + EXP2(z)), 1.f)

// ws layout (floats), 4440 total — copied verbatim to LDS by each main block:
//   [0..79]      Ag       [80..159] Cg      [160..239] K0      (layer-0, exp2-prescaled)
//   [240..242]   va, cov, vc
//   [256..1855]  Wihg (80x20)   [1856..3455] Whhg (80x20)      (exp2-prescaled)
//   [3456..3535] K1
//   [3536..3935] Gih (20x20)    [3936..4335] Ghh (20x20)
//   [4336..4355] sgc0  [4356..4375] sbc0  [4376..4395] sgc1  [4396..4415] sbc1
//   [4416..4435] Wo    [4436] bo   [4437..4439] pad
__global__ void ml_precompute(
    const float* __restrict__ W1, const float* __restrict__ b1,
    const float* __restrict__ Wih, const float* __restrict__ Whh,
    const float* __restrict__ b_ih, const float* __restrict__ b_hh,
    const float* __restrict__ g_x, const float* __restrict__ be_x,
    const float* __restrict__ g_h, const float* __restrict__ be_h,
    const float* __restrict__ g_c, const float* __restrict__ be_c,
    const float* __restrict__ Wo, const float* __restrict__ bo,
    float* __restrict__ ws)
{
    __shared__ float A[G4], C[G4];
    __shared__ float cm[2][HN];
    __shared__ float stats[3];
    __shared__ float Wc[1600], Vc[1600];
    const int t = threadIdx.x;

    if (t < G4) {
        float a = 0.f, c = 0.f;
        for (int k = 0; k < HN; ++k) {
            float w = Wih[t * HN + k];
            a += w * W1[k];
            c += w * b1[k];
        }
        A[t] = a; C[t] = c;
    }
    if (t >= 128 && t < 128 + 2 * HN) {
        int k = (t - 128) % HN;
        const float* src = ((t - 128) < HN) ? (Wih + 1600) : (Whh + 1600);
        float s = 0.f;
        for (int j = 0; j < G4; ++j) s += src[j * HN + k];
        cm[(t - 128) / HN][k] = s * (1.f / 80.f);
    }
    __syncthreads();

    for (int idx = t; idx < 1600; idx += blockDim.x) {
        int k = idx % HN;
        Wc[idx] = Wih[1600 + idx] - cm[0][k];
        Vc[idx] = Whh[1600 + idx] - cm[1][k];
    }
    if (t == 0) {
        float am = 0.f, c_m = 0.f;
        for (int j = 0; j < G4; ++j) { am += A[j]; c_m += C[j]; }
        am *= (1.f / 80.f); c_m *= (1.f / 80.f);
        float va = 0.f, cov = 0.f, vc = 0.f;
        for (int j = 0; j < G4; ++j) {
            float ah = A[j] - am, ch = C[j] - c_m;
            va += ah * ah; cov += ah * ch; vc += ch * ch;
            A[j] = ah; C[j] = ch;
        }
        stats[0] = va * (1.f / 80.f);
        stats[1] = cov * (1.f / 80.f);
        stats[2] = vc * (1.f / 80.f);
    }
    __syncthreads();

    // Gram matrices (unscaled centered)
    for (int e = t; e < 800; e += blockDim.x) {
        int m = e / 400, kl = e % 400, k = kl / HN, l = kl % HN;
        const float* src = m ? Vc : Wc;
        float s = 0.f;
        for (int j = 0; j < G4; ++j) s += src[j * HN + k] * src[j * HN + l];
        ws[3536 + m * 400 + kl] = s * (1.f / 80.f);
    }
    // gain-, sign-, and exp2-scaled gate weights
    for (int idx = t; idx < 1600; idx += blockDim.x) {
        int j = idx / HN;
        float sc = (j >= 40 && j < 60) ? (2.f * L2E) : (-L2E);
        ws[256 + idx]  = Wc[idx] * g_x[80 + j] * sc;
        ws[1856 + idx] = Vc[idx] * g_h[80 + j] * sc;
    }
    if (t < G4) {
        float sc = (t >= 40 && t < 60) ? (2.f * L2E) : (-L2E);
        ws[t]        = A[t] * g_x[t] * sc;
        ws[80 + t]   = C[t] * g_x[t] * sc;
        ws[160 + t]  = (be_x[t] + be_h[t] + b_ih[t] + b_hh[t]) * sc;
        float k1 = be_x[80 + t] + be_h[80 + t] + b_ih[80 + t] + b_hh[80 + t];
        if (t >= 20 && t < 40) k1 += 1.0f;  // forget-gate bias folded
        ws[3456 + t] = k1 * sc;
    }
    if (t < 3) ws[240 + t] = stats[t];
    if (t < HN) {
        ws[4336 + t] = g_c[t] * (2.f * L2E);
        ws[4356 + t] = be_c[t] * (2.f * L2E);
        ws[4376 + t] = g_c[HN + t] * (2.f * L2E);
        ws[4396 + t] = be_c[HN + t] * (2.f * L2E);
        ws[4416 + t] = Wo[t];
    }
    if (t == 0) { ws[4436] = bo[0]; ws[4437] = 0.f; ws[4438] = 0.f; ws[4439] = 0.f; }
}

// ---------------- main kernel: 1 thread per coordinate ---------------------
// All constants staged in LDS (uniform ds_read_b128, literal offsets, broadcast).
// Per-thread state in LDS, bf16-packed. h0 in five named v4f quads.
#define REP20(M) M(0) M(1) M(2) M(3) M(4) M(5) M(6) M(7) M(8) M(9) \
                 M(10) M(11) M(12) M(13) M(14) M(15) M(16) M(17) M(18) M(19)

__device__ __forceinline__ unsigned int bfr(float f) {   // f32 -> bf16 bits (round-half-up)
    return (__float_as_uint(f) + 0x8000u) >> 16;
}
__device__ __forceinline__ float bfu(unsigned int b) {   // bf16 bits (low16) -> f32
    return __uint_as_float(b << 16);
}

// length-20 dot of LDS weights at float-offset OFF against Hq0..Hq4
#define DOT20L(RES, OFF) {                                                  \
    v4f w0_ = *(const v4f*)&LW[(OFF)];                                      \
    v4f w1_ = *(const v4f*)&LW[(OFF) + 4];                                  \
    v4f w2_ = *(const v4f*)&LW[(OFF) + 8];                                  \
    v4f w3_ = *(const v4f*)&LW[(OFF) + 12];                                 \
    v4f w4_ = *(const v4f*)&LW[(OFF) + 16];                                 \
    v4f a_ = __builtin_elementwise_fma(w0_, Hq0, (v4f){0.f,0.f,0.f,0.f});   \
    v4f b_ = __builtin_elementwise_fma(w1_, Hq1, (v4f){0.f,0.f,0.f,0.f});   \
    a_ = __builtin_elementwise_fma(w2_, Hq2, a_);                           \
    b_ = __builtin_elementwise_fma(w3_, Hq3, b_);                           \
    a_ = __builtin_elementwise_fma(w4_, Hq4, a_);                           \
    a_ = a_ + b_;                                                           \
    v2f lo_ = __builtin_shufflevector(a_, a_, 0, 1);                        \
    v2f hi_ = __builtin_shufflevector(a_, a_, 2, 3);                        \
    v2f s_ = lo_ + hi_;                                                     \
    RES = s_[0] + s_[1]; }

__global__ __launch_bounds__(256, 4) void ml_main(
    const float* __restrict__ x_t,
    const float* __restrict__ ws,
    float* __restrict__ out, int n)
{
    __shared__ __align__(16) float LW[4440];          // staged constants
    __shared__ unsigned int SS[HN * 256];             // bf16-packed per-thread state
    const int tid = threadIdx.x;

    // ---- stage constants: 1110 float4 loads, coalesced ----
    {
        const v4f* gsrc = (const v4f*)ws;
        v4f* ldst = (v4f*)LW;
#pragma unroll
        for (int r = 0; r < 5; ++r) {
            int idx = tid + r * 256;
            if (idx < 1110) ldst[idx] = gsrc[idx];
        }
    }
    __syncthreads();

    const int i = blockIdx.x * blockDim.x + tid;
    if (i >= n) return;
    const float x = x_t[i];

    const float va = LW[240], cov = LW[241], vc = LW[242];
    const float rs0 = RSQ(fmaf(va * x, x, fmaf(2.f * cov, x, vc)) + EPSC);

    // ---- layer 0 (f-gate dead: cx=0) ----
    float mu = 0.f, m2 = 0.f;
#define L0A(k) float c0_##k; {                                              \
    float zi_ = fmaf(fmaf(LW[k], x, LW[80 + k]), rs0, LW[160 + k]);         \
    float zg_ = fmaf(fmaf(LW[40 + k], x, LW[120 + k]), rs0, LW[200 + k]);   \
    c0_##k = SIG2(zi_) * TANH2(zg_);                                        \
    mu += c0_##k; m2 = fmaf(c0_##k, c0_##k, m2); }
    REP20(L0A)
    mu *= 0.05f;
    const float rsc = RSQ(fmaf(m2, 0.05f, -mu * mu) + EPSC);
#define L0B(k) float h_##k; {                                               \
    float zo_ = fmaf(fmaf(LW[60 + k], x, LW[140 + k]), rs0, LW[220 + k]);   \
    float tn_ = TANH2(fmaf((c0_##k - mu) * rsc, LW[4336 + k], LW[4356 + k])); \
    h_##k = SIG2(zo_) * tn_;                                                \
    SS[k * 256 + tid] = bfr(c0_##k); }
    REP20(L0B)

    const v4f Hq0 = {h_0,  h_1,  h_2,  h_3};
    const v4f Hq1 = {h_4,  h_5,  h_6,  h_7};
    const v4f Hq2 = {h_8,  h_9,  h_10, h_11};
    const v4f Hq3 = {h_12, h_13, h_14, h_15};
    const v4f Hq4 = {h_16, h_17, h_18, h_19};

    // ---- layer-1 variances via Gram quadratic forms (before the matvec) ----
    float su = 0.f, sv = 0.f;
#define GRAMK(k, q, e) { float du_, dv_;                                    \
    DOT20L(du_, 3536 + k * 20); DOT20L(dv_, 3936 + k * 20);                 \
    su = fmaf(du_, Hq##q[e], su); sv = fmaf(dv_, Hq##q[e], sv); }
    GRAMK(0,0,0)  GRAMK(1,0,1)  GRAMK(2,0,2)  GRAMK(3,0,3)
    GRAMK(4,1,0)  GRAMK(5,1,1)  GRAMK(6,1,2)  GRAMK(7,1,3)
    GRAMK(8,2,0)  GRAMK(9,2,1)  GRAMK(10,2,2) GRAMK(11,2,3)
    GRAMK(12,3,0) GRAMK(13,3,1) GRAMK(14,3,2) GRAMK(15,3,3)
    GRAMK(16,4,0) GRAMK(17,4,1) GRAMK(18,4,2) GRAMK(19,4,3)
    const float rsu = RSQ(su + EPSC);
    const float rsv = RSQ(sv + EPSC);

    // ---- layer 1: streamed gates; state bf16-packed {zo|c1} in LDS ----
    float mu1 = 0.f, m21 = 0.f;
#pragma unroll 2
    for (int k = 0; k < HN; ++k) {
        float dwi_, dvi_, dwf_, dvf_, dwg_, dvg_, dwo_, dvo_;
        DOT20L(dwi_, 256 + k * 20);         DOT20L(dvi_, 1856 + k * 20);
        DOT20L(dwf_, 256 + 400 + k * 20);   DOT20L(dvf_, 1856 + 400 + k * 20);
        DOT20L(dwg_, 256 + 800 + k * 20);   DOT20L(dvg_, 1856 + 800 + k * 20);
        DOT20L(dwo_, 256 + 1200 + k * 20);  DOT20L(dvo_, 1856 + 1200 + k * 20);
        float zi_ = fmaf(dwi_, rsu, fmaf(dvi_, rsv, LW[3456 + k]));
        float zf_ = fmaf(dwf_, rsu, fmaf(dvf_, rsv, LW[3476 + k]));
        float zg_ = fmaf(dwg_, rsu, fmaf(dvg_, rsv, LW[3496 + k]));
        float zo_ = fmaf(dwo_, rsu, fmaf(dvo_, rsv, LW[3516 + k]));
        float c0k = bfu(SS[k * 256 + tid]);
        float c1f = fmaf(SIG2(zf_), c0k, SIG2(zi_) * TANH2(zg_));
        unsigned int c1r = bfr(c1f);
        SS[k * 256 + tid] = (bfr(zo_) << 16) | c1r;
        float c1k = bfu(c1r);                 // use rounded value for LN stats
        mu1 += c1k; m21 = fmaf(c1k, c1k, m21);
    }
    mu1 *= 0.05f;
    const float rsc1 = RSQ(fmaf(m21, 0.05f, -mu1 * mu1) + EPSC);

    float acc = LW[4436];
#pragma unroll 2
    for (int k = 0; k < HN; ++k) {
        unsigned int p = SS[k * 256 + tid];
        float c1k = bfu(p & 0xFFFFu);
        float zok = __uint_as_float(p & 0xFFFF0000u);
        float tn_ = TANH2(fmaf((c1k - mu1) * rsc1, LW[4376 + k], LW[4396 + k]));
        acc = fmaf(SIG2(zok) * tn_, LW[4416 + k], acc);
    }
    out[i] = acc;
}

extern "C" void kernel_launch(void* const* d_in, const int* in_sizes, int n_in,
                              void* d_out, int out_size, void* d_ws, size_t ws_size,
                              hipStream_t stream) {
    const float* x_t  = (const float*)d_in[0];
    const float* W1   = (const float*)d_in[1];
    const float* b1   = (const float*)d_in[2];
    const float* Wih  = (const float*)d_in[3];
    const float* Whh  = (const float*)d_in[4];
    const float* b_ih = (const float*)d_in[5];
    const float* b_hh = (const float*)d_in[6];
    const float* g_x  = (const float*)d_in[7];
    const float* be_x = (const float*)d_in[8];
    const float* g_h  = (const float*)d_in[9];
    const float* be_h = (const float*)d_in[10];
    const float* g_c  = (const float*)d_in[11];
    const float* be_c = (const float*)d_in[12];
    const float* Wo   = (const float*)d_in[13];
    const float* bo   = (const float*)d_in[14];
    float* out = (float*)d_out;
    float* ws  = (float*)d_ws;
    const int n = in_sizes[0];

    hipLaunchKernelGGL(ml_precompute, dim3(1), dim3(256), 0, stream,
                       W1, b1, Wih, Whh, b_ih, b_hh, g_x, be_x, g_h, be_h,
                       g_c, be_c, Wo, bo, ws);
    const int blocks = (n + 255) / 256;
    hipLaunchKernelGGL(ml_main, dim3(blocks), dim3(256), 0, stream,
                       x_t, ws, out, n);
}

// Round 8
// 131.238 us; speedup vs baseline: 1.2986x; 1.2986x over previous
//
#include <hip/hip_runtime.h>

#define HN 20
#define G4 80
#define EPSC 1e-5f
#define L2E 1.4426950408889634f

typedef float v2f __attribute__((ext_vector_type(2)));
typedef float f32x4 __attribute__((ext_vector_type(4)));
typedef short short8 __attribute__((ext_vector_type(8)));
typedef int i32x4 __attribute__((ext_vector_type(4)));
typedef int i32x2 __attribute__((ext_vector_type(2)));
typedef unsigned int u32;

#if __has_builtin(__builtin_amdgcn_exp2f)
#define EXP2(x) __builtin_amdgcn_exp2f(x)
#else
#define EXP2(x) __expf((x) * 0.6931471805599453f)
#endif
#define RCP(x) __builtin_amdgcn_rcpf(x)
#define RSQ(x) __builtin_amdgcn_rsqf(x)
#define SIG2(z) RCP(1.f + EXP2(z))                  // z pre-scaled by -L2E
#define TANH2(z) fmaf(-2.f, RCP(1.f + EXP2(z)), 1.f) // z pre-scaled by +2*L2E

__device__ __forceinline__ u32 bfr(float f) { return (__float_as_uint(f) + 0x8000u) >> 16; }
__device__ __forceinline__ float bfu(u32 b) { return __uint_as_float(b << 16); }

// ws layout (floats):
//   [0..79] Ag  [80..159] Cg  [160..239] K0   (layer-0, exp2-prescaled)
//   [240..242] va, cov, vc
//   [4336..4355] sgc0  [4356..4375] sbc0      (layer-0 c-LN, 2L2E-scaled)
//   [4436] bo
//   [4440..4759] colTab: 80 x float4 {GS, GH, K1s, ab(bf16 pair a|b)}
//   [4760..4839] kTab:   20 x float4 {sgc1*2L2E, sbc1*2L2E, Wo/4, 0}
//   [4840..6119] Bfrag:  5120 bf16 (ushort) = 10 tiles x 64 lanes x 8 elems
__global__ void ml_precompute(
    const float* __restrict__ W1, const float* __restrict__ b1,
    const float* __restrict__ Wih, const float* __restrict__ Whh,
    const float* __restrict__ b_ih, const float* __restrict__ b_hh,
    const float* __restrict__ g_x, const float* __restrict__ be_x,
    const float* __restrict__ g_h, const float* __restrict__ be_h,
    const float* __restrict__ g_c, const float* __restrict__ be_c,
    const float* __restrict__ Wo, const float* __restrict__ bo,
    float* __restrict__ ws)
{
    __shared__ float A[G4], C[G4];
    __shared__ float cm[2][HN];
    __shared__ float stats[3];
    __shared__ float Wc[1600], Vc[1600];
    const int t = threadIdx.x;

    if (t < G4) {
        float a = 0.f, c = 0.f;
        for (int k = 0; k < HN; ++k) {
            float w = Wih[t * HN + k];
            a += w * W1[k];
            c += w * b1[k];
        }
        A[t] = a; C[t] = c;
    }
    if (t >= 128 && t < 128 + 2 * HN) {
        int k = (t - 128) % HN;
        const float* src = ((t - 128) < HN) ? (Wih + 1600) : (Whh + 1600);
        float s = 0.f;
        for (int j = 0; j < G4; ++j) s += src[j * HN + k];
        cm[(t - 128) / HN][k] = s * (1.f / 80.f);
    }
    __syncthreads();

    for (int idx = t; idx < 1600; idx += blockDim.x) {
        int k = idx % HN;
        Wc[idx] = Wih[1600 + idx] - cm[0][k];
        Vc[idx] = Whh[1600 + idx] - cm[1][k];
    }
    if (t == 0) {
        float am = 0.f, c_m = 0.f;
        for (int j = 0; j < G4; ++j) { am += A[j]; c_m += C[j]; }
        am *= (1.f / 80.f); c_m *= (1.f / 80.f);
        float va = 0.f, cov = 0.f, vc = 0.f;
        for (int j = 0; j < G4; ++j) {
            float ah = A[j] - am, ch = C[j] - c_m;
            va += ah * ah; cov += ah * ch; vc += ch * ch;
            A[j] = ah; C[j] = ch;
        }
        stats[0] = va * (1.f / 80.f);
        stats[1] = cov * (1.f / 80.f);
        stats[2] = vc * (1.f / 80.f);
    }
    __syncthreads();

    // layer-0 constants (exp2-prescaled, sigmoid sign folded)
    if (t < G4) {
        float sc = (t >= 40 && t < 60) ? (2.f * L2E) : (-L2E);
        ws[t]       = A[t] * g_x[t] * sc;
        ws[80 + t]  = C[t] * g_x[t] * sc;
        ws[160 + t] = (be_x[t] + be_h[t] + b_ih[t] + b_hh[t]) * sc;
    }
    if (t < 3) ws[240 + t] = stats[t];
    if (t < HN) {
        ws[4336 + t] = g_c[t] * (2.f * L2E);
        ws[4356 + t] = be_c[t] * (2.f * L2E);
    }
    if (t == 0) ws[4436] = bo[0];

    // colTab: per z-col C = 4*kh + g  (g: 0=i,1=f,2=g,3=o)
    if (t < G4) {
        int g = t & 3, kh = t >> 2, row = g * 20 + kh;
        float sc = (g == 2) ? (2.f * L2E) : (-L2E);
        float k1 = be_x[80 + row] + be_h[80 + row] + b_ih[80 + row] + b_hh[80 + row]
                 + ((g == 1) ? 1.f : 0.f);
        float aa = (g == 2) ? 1.f : 0.f;
        float bb = (g == 2) ? -2.f : 1.f;
        ws[4440 + 4 * t + 0] = g_x[80 + row] * sc;
        ws[4440 + 4 * t + 1] = g_h[80 + row] * sc;
        ws[4440 + 4 * t + 2] = k1 * sc;
        ws[4440 + 4 * t + 3] = __uint_as_float(bfr(aa) | (bfr(bb) << 16));
    }
    // kTab
    if (t < HN) {
        ws[4760 + 4 * t + 0] = g_c[HN + t] * (2.f * L2E);
        ws[4760 + 4 * t + 1] = be_c[HN + t] * (2.f * L2E);
        ws[4760 + 4 * t + 2] = Wo[t] * 0.25f;
        ws[4760 + 4 * t + 3] = 0.f;
    }
    // B fragments: tile tt (0-4: Wihc u-side, 5-9: Whhc v-side), lane l, elem j
    // B[k][col]: lane holds k = (l>>4)*8 + j, col = l&15; global col C = 16*(tt%5)+col
    {
        unsigned short* bf = (unsigned short*)(ws + 4840);
        for (int e = t; e < 5120; e += blockDim.x) {
            int tt = e >> 9;
            int l = (e >> 3) & 63;
            int j = e & 7;
            int k = ((l >> 4) << 3) + j;
            int Cc = (((tt % 5) << 4) + (l & 15));
            int g = Cc & 3, kh = Cc >> 2;
            const float* src = (tt < 5) ? Wc : Vc;
            float val = (k < HN) ? src[(g * 20 + kh) * HN + k] : 0.f;
            bf[e] = (unsigned short)bfr(val);
        }
    }
}

// ------------------------------ main kernel --------------------------------
#define REP20(M) M(0) M(1) M(2) M(3) M(4) M(5) M(6) M(7) M(8) M(9) \
                 M(10) M(11) M(12) M(13) M(14) M(15) M(16) M(17) M(18) M(19)
#define FOR_T(M) M(0) M(1) M(2) M(3) M(4)
#define R4F(M) M(0) M(1) M(2) M(3)

#define DPPF(x, ctrl) __int_as_float(__builtin_amdgcn_mov_dpp(__float_as_int(x), (ctrl), 0xf, 0xf, true))
#define RED16(s) do { s += DPPF(s, 0x128); s += DPPF(s, 0x124); \
                      s += DPPF(s, 0x122); s += DPPF(s, 0x121); } while (0)

__global__ __launch_bounds__(256, 3) void ml_main(
    const float* __restrict__ x_t,
    const float* __restrict__ ws,
    float* __restrict__ out, int n)
{
    __shared__ unsigned short At[4][64 * 40];   // A-tiles: row=coord(64), 40 bf16 (80B), k<32
    __shared__ unsigned short C0s[4][64 * 40];  // c0 packed bf16: [coord][q*8 + t]
    __shared__ f32x4 LT[100];                   // colTab(80) + kTab(20)
    const int tid = threadIdx.x, wv = tid >> 6, l = tid & 63;

    if (tid < 100) LT[tid] = ((const f32x4*)ws)[1110 + tid];

    // B fragments: 10 coalesced 16B loads per lane (issued early, hide under phase 1)
    const short8* __restrict__ bfp = (const short8*)(ws + 4840);
    short8 B0 = bfp[0 * 64 + l], B1 = bfp[1 * 64 + l], B2 = bfp[2 * 64 + l],
           B3 = bfp[3 * 64 + l], B4 = bfp[4 * 64 + l], B5 = bfp[5 * 64 + l],
           B6 = bfp[6 * 64 + l], B7 = bfp[7 * 64 + l], B8 = bfp[8 * 64 + l],
           B9 = bfp[9 * 64 + l];

    // ---- phase 1: per-lane closed-form layer 0 ----
    const int gi0 = blockIdx.x * 256 + tid;
    const float x = (gi0 < n) ? x_t[gi0] : 0.f;
    const float* __restrict__ Ag = ws;
    const float* __restrict__ Cg = ws + 80;
    const float* __restrict__ K0 = ws + 160;
    const float* __restrict__ sg0 = ws + 4336;
    const float* __restrict__ sb0 = ws + 4356;
    const float va = ws[240], cov = ws[241], vc = ws[242];
    const float rs0 = RSQ(fmaf(va * x, x, fmaf(2.f * cov, x, vc)) + EPSC);

    float mu = 0.f, m2 = 0.f;
#define L0A(k) float c0_##k; {                                              \
    float zi_ = fmaf(fmaf(Ag[k], x, Cg[k]), rs0, K0[k]);                    \
    float zg_ = fmaf(fmaf(Ag[40 + k], x, Cg[40 + k]), rs0, K0[40 + k]);     \
    c0_##k = SIG2(zi_) * TANH2(zg_);                                        \
    mu += c0_##k; m2 = fmaf(c0_##k, c0_##k, m2); }
    REP20(L0A)
    mu *= 0.05f;
    const float rsc = RSQ(fmaf(m2, 0.05f, -mu * mu) + EPSC);
#define L0B(k) float h_##k; {                                               \
    float zo_ = fmaf(fmaf(Ag[60 + k], x, Cg[60 + k]), rs0, K0[60 + k]);     \
    float tn_ = TANH2(fmaf((c0_##k - mu) * rsc, sg0[k], sb0[k]));           \
    h_##k = SIG2(zo_) * tn_; }
    REP20(L0B)

    // A-tile write: 40 bf16 per row (k0..19 = h, k20..31 = 0, rest pad)
    {
        unsigned short* arow = &At[wv][l * 40];
#define PKH(a,b) ((int)(bfr(h_##a) | (bfr(h_##b) << 16)))
        i32x4 aw0; aw0[0] = PKH(0,1); aw0[1] = PKH(2,3); aw0[2] = PKH(4,5); aw0[3] = PKH(6,7);
        i32x4 aw1; aw1[0] = PKH(8,9); aw1[1] = PKH(10,11); aw1[2] = PKH(12,13); aw1[3] = PKH(14,15);
        i32x2 aw2; aw2[0] = PKH(16,17); aw2[1] = PKH(18,19);
        i32x2 zz2; zz2[0] = 0; zz2[1] = 0;
        i32x4 zz4; zz4[0] = 0; zz4[1] = 0; zz4[2] = 0; zz4[3] = 0;
        *(i32x4*)(arow + 0)  = aw0;
        *(i32x4*)(arow + 8)  = aw1;
        *(i32x2*)(arow + 16) = aw2;
        *(i32x2*)(arow + 20) = zz2;
        *(i32x4*)(arow + 24) = zz4;
        // c0 packed: group q holds k = 4t+q for t=0..4 (slots 5..7 zero)
        unsigned short* crow = &C0s[wv][l * 40];
#define PKC(a,b) ((int)(bfr(c0_##a) | (bfr(c0_##b) << 16)))
#define PKC1(a)  ((int)bfr(c0_##a))
        i32x4 cw;
        cw[0] = PKC(0,4);  cw[1] = PKC(8,12);  cw[2] = PKC1(16); cw[3] = 0; *(i32x4*)(crow + 0)  = cw;
        cw[0] = PKC(1,5);  cw[1] = PKC(9,13);  cw[2] = PKC1(17); cw[3] = 0; *(i32x4*)(crow + 8)  = cw;
        cw[0] = PKC(2,6);  cw[1] = PKC(10,14); cw[2] = PKC1(18); cw[3] = 0; *(i32x4*)(crow + 16) = cw;
        cw[0] = PKC(3,7);  cw[1] = PKC(11,15); cw[2] = PKC1(19); cw[3] = 0; *(i32x4*)(crow + 24) = cw;
    }
    __syncthreads();

    // ---- phase 3: MFMA + in-fragment LSTM epilogue ----
    const float bo_ = ws[4436];
    const int c16 = l & 15, hi = l >> 4, q = c16 >> 2;
    f32x4 z4; z4[0] = 0.f; z4[1] = 0.f; z4[2] = 0.f; z4[3] = 0.f;

    for (int af = 0; af < 4; ++af) {
        short8 a8 = *(const short8*)&At[wv][(af * 16 + c16) * 40 + hi * 8];
        f32x4 U0 = __builtin_amdgcn_mfma_f32_16x16x32_bf16(a8, B0, z4, 0, 0, 0);
        f32x4 U1 = __builtin_amdgcn_mfma_f32_16x16x32_bf16(a8, B1, z4, 0, 0, 0);
        f32x4 U2 = __builtin_amdgcn_mfma_f32_16x16x32_bf16(a8, B2, z4, 0, 0, 0);
        f32x4 U3 = __builtin_amdgcn_mfma_f32_16x16x32_bf16(a8, B3, z4, 0, 0, 0);
        f32x4 U4 = __builtin_amdgcn_mfma_f32_16x16x32_bf16(a8, B4, z4, 0, 0, 0);
        f32x4 V0 = __builtin_amdgcn_mfma_f32_16x16x32_bf16(a8, B5, z4, 0, 0, 0);
        f32x4 V1 = __builtin_amdgcn_mfma_f32_16x16x32_bf16(a8, B6, z4, 0, 0, 0);
        f32x4 V2 = __builtin_amdgcn_mfma_f32_16x16x32_bf16(a8, B7, z4, 0, 0, 0);
        f32x4 V3 = __builtin_amdgcn_mfma_f32_16x16x32_bf16(a8, B8, z4, 0, 0, 0);
        f32x4 V4 = __builtin_amdgcn_mfma_f32_16x16x32_bf16(a8, B9, z4, 0, 0, 0);

        // c0 for this lane's quad-slot: one b128 per reg r
        i32x4 c0q_0 = *(const i32x4*)&C0s[wv][(af * 16 + hi * 4 + 0) * 40 + q * 8];
        i32x4 c0q_1 = *(const i32x4*)&C0s[wv][(af * 16 + hi * 4 + 1) * 40 + q * 8];
        i32x4 c0q_2 = *(const i32x4*)&C0s[wv][(af * 16 + hi * 4 + 2) * 40 + q * 8];
        i32x4 c0q_3 = *(const i32x4*)&C0s[wv][(af * 16 + hi * 4 + 3) * 40 + q * 8];

        // LN variances via in-fragment squares + 16-lane DPP reduce
        f32x4 su4 = U0 * U0;
        su4 = __builtin_elementwise_fma(U1, U1, su4);
        su4 = __builtin_elementwise_fma(U2, U2, su4);
        su4 = __builtin_elementwise_fma(U3, U3, su4);
        su4 = __builtin_elementwise_fma(U4, U4, su4);
        f32x4 sv4 = V0 * V0;
        sv4 = __builtin_elementwise_fma(V1, V1, sv4);
        sv4 = __builtin_elementwise_fma(V2, V2, sv4);
        sv4 = __builtin_elementwise_fma(V3, V3, sv4);
        sv4 = __builtin_elementwise_fma(V4, V4, sv4);
        f32x4 rsu4, rsv4;
#define RSUR(r) { float s_ = su4[r]; RED16(s_); rsu4[r] = RSQ(fmaf(s_, 0.0125f, EPSC)); \
                  float t_ = sv4[r]; RED16(t_); rsv4[r] = RSQ(fmaf(t_, 0.0125f, EPSC)); }
        R4F(RSUR)

        // pass A: z -> activation -> quad broadcasts -> c1, pack {sigma_o|c1}
        f32x4 mu1a = z4, m21a = z4;
#define DPC(t) u32 pc_##t##_0, pc_##t##_1, pc_##t##_2, pc_##t##_3;
        FOR_T(DPC)
#define PA_R(t, r) { \
    float z_ = fmaf(U##t[r] * GS_, rsu4[r], fmaf(V##t[r] * GH_, rsv4[r], K1_)); \
    float w_ = fmaf(bv_, RCP(1.f + EXP2(z_)), av_); \
    float wi_ = DPPF(w_, 0x00); float wf_ = DPPF(w_, 0x55); \
    float wg_ = DPPF(w_, 0xAA); float wo_ = DPPF(w_, 0xFF); \
    float c0v_ = bfu(((u32)c0q_##r[(t) >> 1] >> (((t) & 1) * 16)) & 0xffffu); \
    float c1_ = fmaf(wf_, c0v_, wi_ * wg_); \
    u32 pv_ = (bfr(wo_) << 16) | bfr(c1_); \
    pc_##t##_##r = pv_; \
    float c1r_ = bfu(pv_ & 0xffffu); \
    mu1a[r] += c1r_; m21a[r] = fmaf(c1r_, c1r_, m21a[r]); }
#define PASSA(t) { f32x4 f4_ = LT[16 * (t) + c16]; \
    float GS_ = f4_[0], GH_ = f4_[1], K1_ = f4_[2]; \
    u32 ab_ = __float_as_uint(f4_[3]); \
    float av_ = bfu(ab_ & 0xffffu), bv_ = bfu(ab_ >> 16); \
    PA_R(t, 0) PA_R(t, 1) PA_R(t, 2) PA_R(t, 3) }
        FOR_T(PASSA)

        // LN-1 stats per coord
        f32x4 mu1v, rsc1v;
#define STATR(r) { float s1_ = mu1a[r]; RED16(s1_); float s2_ = m21a[r]; RED16(s2_); \
    float mu_ = s1_ * 0.0125f; mu1v[r] = mu_; \
    rsc1v[r] = RSQ(fmaf(mu_, -mu_, s2_ * 0.0125f) + EPSC); }
        R4F(STATR)

        // pass B: h1 = sigma_o * tanh(LN(c1)); out partial = h1 * Wo/4
        f32x4 oac = z4;
#define PB_R(t, r) { u32 p_ = pc_##t##_##r; \
    float c1v_ = bfu(p_ & 0xffffu); float so_ = bfu(p_ >> 16); \
    float tn_ = TANH2(fmaf((c1v_ - mu1v[r]) * rsc1v[r], kt_[0], kt_[1])); \
    oac[r] = fmaf(so_ * tn_, kt_[2], oac[r]); }
#define PASSB(t) { f32x4 kt_ = LT[80 + 4 * (t) + q]; \
    PB_R(t, 0) PB_R(t, 1) PB_R(t, 2) PB_R(t, 3) }
        FOR_T(PASSB)

        // row-reduce (x4 replication folded into Wo/4) and store
        const int gibase = blockIdx.x * 256 + wv * 64 + af * 16;
#define OUTR(r) { float o_ = oac[r]; RED16(o_); \
    if (c16 == (r)) { int gi_ = gibase + hi * 4 + (r); \
        if (gi_ < n) out[gi_] = o_ + bo_; } }
        R4F(OUTR)
    }
}

extern "C" void kernel_launch(void* const* d_in, const int* in_sizes, int n_in,
                              void* d_out, int out_size, void* d_ws, size_t ws_size,
                              hipStream_t stream) {
    const float* x_t  = (const float*)d_in[0];
    const float* W1   = (const float*)d_in[1];
    const float* b1   = (const float*)d_in[2];
    const float* Wih  = (const float*)d_in[3];
    const float* Whh  = (const float*)d_in[4];
    const float* b_ih = (const float*)d_in[5];
    const float* b_hh = (const float*)d_in[6];
    const float* g_x  = (const float*)d_in[7];
    const float* be_x = (const float*)d_in[8];
    const float* g_h  = (const float*)d_in[9];
    const float* be_h = (const float*)d_in[10];
    const float* g_c  = (const float*)d_in[11];
    const float* be_c = (const float*)d_in[12];
    const float* Wo   = (const float*)d_in[13];
    const float* bo   = (const float*)d_in[14];
    float* out = (float*)d_out;
    float* ws  = (float*)d_ws;
    const int n = in_sizes[0];

    hipLaunchKernelGGL(ml_precompute, dim3(1), dim3(256), 0, stream,
                       W1, b1, Wih, Whh, b_ih, b_hh, g_x, be_x, g_h, be_h,
                       g_c, be_c, Wo, bo, ws);
    const int blocks = (n + 255) / 256;
    hipLaunchKernelGGL(ml_main, dim3(blocks), dim3(256), 0, stream,
                       x_t, ws, out, n);
}

// Round 9
// 93.557 us; speedup vs baseline: 1.8216x; 1.4028x over previous
//
#include <hip/hip_runtime.h>

#define HN 20
#define G4 80
#define EPSC 1e-5f
#define L2E 1.4426950408889634f

typedef float v2f __attribute__((ext_vector_type(2)));
typedef float f32x4 __attribute__((ext_vector_type(4)));
typedef short short8 __attribute__((ext_vector_type(8)));
typedef int i32x4 __attribute__((ext_vector_type(4)));
typedef int i32x2 __attribute__((ext_vector_type(2)));
typedef unsigned int u32;

#if __has_builtin(__builtin_amdgcn_exp2f)
#define EXP2(x) __builtin_amdgcn_exp2f(x)
#else
#define EXP2(x) __expf((x) * 0.6931471805599453f)
#endif
#define RCP(x) __builtin_amdgcn_rcpf(x)
#define RSQ(x) __builtin_amdgcn_rsqf(x)
#define SIG2(z) RCP(1.f + EXP2(z))                   // z pre-scaled by -L2E
#define TANH2(z) fmaf(-2.f, RCP(1.f + EXP2(z)), 1.f) // z pre-scaled by +2*L2E

__device__ __forceinline__ u32 bfr(float f) { return (__float_as_uint(f) + 0x8000u) >> 16; }
__device__ __forceinline__ float bfu(u32 b) { return __uint_as_float(b << 16); }

// ws layout (floats):
//   [0..79] Ag  [80..159] Cg  [160..239] K0     (layer-0, exp2-prescaled)
//   [240..242] va, cov, vc
//   [256..575]  colTab: 80 x f32x4 {GS, GH, K1s, ab}   (entry 16*tau + c)
//   [576..639]  kTab main: 16 x f32x4 {sgc1, sbc1, Wo[c], 0}
//   [640..703]  kTab4:     16 x f32x4 {sgc1[u], sbc1[u], Wo[u]/4, 0}, u=16+(c>>2)
//   [704..3263] Bfrag: 5120 bf16 = 10 tiles x 64 lanes x 8 elems
//   [4336..4355] sgc0  [4356..4375] sbc0        (layer-0 c-LN, 2L2E-scaled)
//   [4436] bo
// B column map: tile tau(=tt%5)<4: col c -> gate tau of unit c (units 0..15);
//               tau=4: col c -> gate (c&3) of unit 16+(c>>2).
__global__ void ml_precompute(
    const float* __restrict__ W1, const float* __restrict__ b1,
    const float* __restrict__ Wih, const float* __restrict__ Whh,
    const float* __restrict__ b_ih, const float* __restrict__ b_hh,
    const float* __restrict__ g_x, const float* __restrict__ be_x,
    const float* __restrict__ g_h, const float* __restrict__ be_h,
    const float* __restrict__ g_c, const float* __restrict__ be_c,
    const float* __restrict__ Wo, const float* __restrict__ bo,
    float* __restrict__ ws)
{
    __shared__ float A[G4], C[G4];
    __shared__ float cm[2][HN];
    __shared__ float stats[3];
    __shared__ float Wc[1600], Vc[1600];
    const int t = threadIdx.x;

    if (t < G4) {
        float a = 0.f, c = 0.f;
        for (int k = 0; k < HN; ++k) {
            float w = Wih[t * HN + k];
            a += w * W1[k];
            c += w * b1[k];
        }
        A[t] = a; C[t] = c;
    }
    if (t >= 128 && t < 128 + 2 * HN) {
        int k = (t - 128) % HN;
        const float* src = ((t - 128) < HN) ? (Wih + 1600) : (Whh + 1600);
        float s = 0.f;
        for (int j = 0; j < G4; ++j) s += src[j * HN + k];
        cm[(t - 128) / HN][k] = s * (1.f / 80.f);
    }
    __syncthreads();

    for (int idx = t; idx < 1600; idx += blockDim.x) {
        int k = idx % HN;
        Wc[idx] = Wih[1600 + idx] - cm[0][k];
        Vc[idx] = Whh[1600 + idx] - cm[1][k];
    }
    if (t == 0) {
        float am = 0.f, c_m = 0.f;
        for (int j = 0; j < G4; ++j) { am += A[j]; c_m += C[j]; }
        am *= (1.f / 80.f); c_m *= (1.f / 80.f);
        float va = 0.f, cov = 0.f, vc = 0.f;
        for (int j = 0; j < G4; ++j) {
            float ah = A[j] - am, ch = C[j] - c_m;
            va += ah * ah; cov += ah * ch; vc += ch * ch;
            A[j] = ah; C[j] = ch;
        }
        stats[0] = va * (1.f / 80.f);
        stats[1] = cov * (1.f / 80.f);
        stats[2] = vc * (1.f / 80.f);
    }
    __syncthreads();

    // layer-0 constants (exp2-prescaled, sigmoid sign folded)
    if (t < G4) {
        float sc = (t >= 40 && t < 60) ? (2.f * L2E) : (-L2E);
        ws[t]       = A[t] * g_x[t] * sc;
        ws[80 + t]  = C[t] * g_x[t] * sc;
        ws[160 + t] = (be_x[t] + be_h[t] + b_ih[t] + b_hh[t]) * sc;
    }
    if (t < 3) ws[240 + t] = stats[t];
    if (t < HN) {
        ws[4336 + t] = g_c[t] * (2.f * L2E);
        ws[4356 + t] = be_c[t] * (2.f * L2E);
    }
    if (t == 0) ws[4436] = bo[0];

    // colTab: entry t = 16*tau + c
    if (t < G4) {
        int tau = t >> 4, c = t & 15;
        int g, u;
        if (tau < 4) { g = tau; u = c; }
        else         { g = c & 3; u = 16 + (c >> 2); }
        int row = g * 20 + u;
        float sc = (g == 2) ? (2.f * L2E) : (-L2E);
        float k1 = be_x[80 + row] + be_h[80 + row] + b_ih[80 + row] + b_hh[80 + row]
                 + ((g == 1) ? 1.f : 0.f);
        float aa = (g == 2) ? 1.f : 0.f;
        float bb = (g == 2) ? -2.f : 1.f;
        ws[256 + 4 * t + 0] = g_x[80 + row] * sc;
        ws[256 + 4 * t + 1] = g_h[80 + row] * sc;
        ws[256 + 4 * t + 2] = k1 * sc;
        ws[256 + 4 * t + 3] = __uint_as_float(bfr(aa) | (bfr(bb) << 16));
    }
    if (t < 16) {  // kTab main: unit c = t
        ws[576 + 4 * t + 0] = g_c[HN + t] * (2.f * L2E);
        ws[576 + 4 * t + 1] = be_c[HN + t] * (2.f * L2E);
        ws[576 + 4 * t + 2] = Wo[t];
        ws[576 + 4 * t + 3] = 0.f;
    }
    if (t >= 16 && t < 32) {  // kTab4: c = t-16, unit 16+(c>>2)
        int c = t - 16, u = 16 + (c >> 2);
        ws[640 + 4 * c + 0] = g_c[HN + u] * (2.f * L2E);
        ws[640 + 4 * c + 1] = be_c[HN + u] * (2.f * L2E);
        ws[640 + 4 * c + 2] = Wo[u] * 0.25f;
        ws[640 + 4 * c + 3] = 0.f;
    }
    // B fragments
    {
        unsigned short* bf = (unsigned short*)(ws + 704);
        for (int e = t; e < 5120; e += blockDim.x) {
            int tt = e >> 9;          // 0..9
            int l = (e >> 3) & 63;
            int j = e & 7;
            int k = ((l >> 4) << 3) + j;
            int c = l & 15, tau = tt % 5;
            int g, u;
            if (tau < 4) { g = tau; u = c; }
            else         { g = c & 3; u = 16 + (c >> 2); }
            const float* src = (tt < 5) ? Wc : Vc;
            float val = (k < HN) ? src[(g * 20 + u) * HN + k] : 0.f;
            bf[e] = (unsigned short)bfr(val);
        }
    }
}

// ------------------------------ main kernel --------------------------------
#define REP20(M) M(0) M(1) M(2) M(3) M(4) M(5) M(6) M(7) M(8) M(9) \
                 M(10) M(11) M(12) M(13) M(14) M(15) M(16) M(17) M(18) M(19)

#define DPPF(x, ctrl) __int_as_float(__builtin_amdgcn_mov_dpp(__float_as_int(x), (ctrl), 0xf, 0xf, true))
#define RED16(s) do { s += DPPF(s, 0x128); s += DPPF(s, 0x124); \
                      s += DPPF(s, 0x122); s += DPPF(s, 0x121); } while (0)

__global__ __launch_bounds__(256, 3) void ml_main(
    const float* __restrict__ x_t,
    const float* __restrict__ ws,
    float* __restrict__ out, int n)
{
    __shared__ unsigned short At[4][64 * 40];   // [wave][coord][40 bf16] (k<32 zero-padded)
    __shared__ unsigned short C0T[4][HN][68];   // c0 transposed: [wave][unit][coord], pad 68
    __shared__ f32x4 LT[112];                   // colTab(80) + kTab(16) + kTab4(16)
    const int tid = threadIdx.x, wv = tid >> 6, l = tid & 63;

    if (tid < 112) LT[tid] = ((const f32x4*)(ws + 256))[tid];

    // B fragments: 10 coalesced 16B loads per lane (early issue)
    const short8* __restrict__ bfp = (const short8*)(ws + 704);
    short8 B0 = bfp[0 * 64 + l], B1 = bfp[1 * 64 + l], B2 = bfp[2 * 64 + l],
           B3 = bfp[3 * 64 + l], B4 = bfp[4 * 64 + l], B5 = bfp[5 * 64 + l],
           B6 = bfp[6 * 64 + l], B7 = bfp[7 * 64 + l], B8 = bfp[8 * 64 + l],
           B9 = bfp[9 * 64 + l];

    // ---- phase 1: per-lane closed-form layer 0 ----
    const int gi0 = blockIdx.x * 256 + tid;
    const float x = (gi0 < n) ? x_t[gi0] : 0.f;
    const float* __restrict__ Ag = ws;
    const float* __restrict__ Cg = ws + 80;
    const float* __restrict__ K0 = ws + 160;
    const float* __restrict__ sg0 = ws + 4336;
    const float* __restrict__ sb0 = ws + 4356;
    const float va = ws[240], cov = ws[241], vc = ws[242];
    const float rs0 = RSQ(fmaf(va * x, x, fmaf(2.f * cov, x, vc)) + EPSC);

    float mu = 0.f, m2 = 0.f;
#define L0A(k) float c0_##k; {                                              \
    float zi_ = fmaf(fmaf(Ag[k], x, Cg[k]), rs0, K0[k]);                    \
    float zg_ = fmaf(fmaf(Ag[40 + k], x, Cg[40 + k]), rs0, K0[40 + k]);     \
    c0_##k = SIG2(zi_) * TANH2(zg_);                                        \
    mu += c0_##k; m2 = fmaf(c0_##k, c0_##k, m2); }
    REP20(L0A)
    mu *= 0.05f;
    const float rsc = RSQ(fmaf(m2, 0.05f, -mu * mu) + EPSC);
#define L0B(k) float h_##k; {                                               \
    float zo_ = fmaf(fmaf(Ag[60 + k], x, Cg[60 + k]), rs0, K0[60 + k]);     \
    float tn_ = TANH2(fmaf((c0_##k - mu) * rsc, sg0[k], sb0[k]));           \
    h_##k = SIG2(zo_) * tn_; }
    REP20(L0B)

    // A-tile write: 40 bf16 per row (k0..19 = h, rest 0)
    {
        unsigned short* arow = &At[wv][l * 40];
#define PKH(a,b) ((int)(bfr(h_##a) | (bfr(h_##b) << 16)))
        i32x4 aw0; aw0[0] = PKH(0,1); aw0[1] = PKH(2,3); aw0[2] = PKH(4,5); aw0[3] = PKH(6,7);
        i32x4 aw1; aw1[0] = PKH(8,9); aw1[1] = PKH(10,11); aw1[2] = PKH(12,13); aw1[3] = PKH(14,15);
        i32x2 aw2; aw2[0] = PKH(16,17); aw2[1] = PKH(18,19);
        i32x2 zz2; zz2[0] = 0; zz2[1] = 0;
        i32x4 zz4; zz4[0] = 0; zz4[1] = 0; zz4[2] = 0; zz4[3] = 0;
        *(i32x4*)(arow + 0)  = aw0;
        *(i32x4*)(arow + 8)  = aw1;
        *(i32x2*)(arow + 16) = aw2;
        *(i32x2*)(arow + 20) = zz2;
        *(i32x4*)(arow + 24) = zz4;
    }
    // c0 transposed store: [unit][coord]
#define C0W(k) C0T[wv][k][l] = (unsigned short)bfr(c0_##k);
    REP20(C0W)
    __syncthreads();

    // ---- phase 3: MFMA + lane-owns-unit epilogue ----
    const int c16 = l & 15, hi = l >> 4, q = c16 >> 2;
    const f32x4 ct0 = LT[c16],      ct1 = LT[16 + c16], ct2 = LT[32 + c16],
                ct3 = LT[48 + c16], ct4 = LT[64 + c16];
    const f32x4 km = LT[80 + c16], k4 = LT[96 + c16];
    const u32 ab4 = __float_as_uint(ct4[3]);
    const float a4 = bfu(ab4 & 0xffffu), b4 = bfu(ab4 >> 16);
    const float bo_ = ws[4436];

    for (int af = 0; af < 4; ++af) {
        short8 a8 = *(const short8*)&At[wv][(af * 16 + c16) * 40 + hi * 8];
        f32x4 z4; z4[0] = 0.f; z4[1] = 0.f; z4[2] = 0.f; z4[3] = 0.f;
        f32x4 U0 = __builtin_amdgcn_mfma_f32_16x16x32_bf16(a8, B0, z4, 0, 0, 0);
        f32x4 U1 = __builtin_amdgcn_mfma_f32_16x16x32_bf16(a8, B1, z4, 0, 0, 0);
        f32x4 U2 = __builtin_amdgcn_mfma_f32_16x16x32_bf16(a8, B2, z4, 0, 0, 0);
        f32x4 U3 = __builtin_amdgcn_mfma_f32_16x16x32_bf16(a8, B3, z4, 0, 0, 0);
        f32x4 U4 = __builtin_amdgcn_mfma_f32_16x16x32_bf16(a8, B4, z4, 0, 0, 0);
        f32x4 V0 = __builtin_amdgcn_mfma_f32_16x16x32_bf16(a8, B5, z4, 0, 0, 0);
        f32x4 V1 = __builtin_amdgcn_mfma_f32_16x16x32_bf16(a8, B6, z4, 0, 0, 0);
        f32x4 V2 = __builtin_amdgcn_mfma_f32_16x16x32_bf16(a8, B7, z4, 0, 0, 0);
        f32x4 V3 = __builtin_amdgcn_mfma_f32_16x16x32_bf16(a8, B8, z4, 0, 0, 0);
        f32x4 V4 = __builtin_amdgcn_mfma_f32_16x16x32_bf16(a8, B9, z4, 0, 0, 0);

        // c0 for this lane: unit c16 (main) and unit 16+q (t4), coords af*16+hi*4+0..3
        i32x2 c0m2 = *(const i32x2*)&C0T[wv][c16][af * 16 + hi * 4];
        i32x2 c0t2 = *(const i32x2*)&C0T[wv][16 + q][af * 16 + hi * 4];

        // LN variances (raw u,v over all 80 cols) via squares + 16-lane DPP reduce
        f32x4 su4 = U0 * U0;
        su4 = __builtin_elementwise_fma(U1, U1, su4);
        su4 = __builtin_elementwise_fma(U2, U2, su4);
        su4 = __builtin_elementwise_fma(U3, U3, su4);
        su4 = __builtin_elementwise_fma(U4, U4, su4);
        f32x4 sv4 = V0 * V0;
        sv4 = __builtin_elementwise_fma(V1, V1, sv4);
        sv4 = __builtin_elementwise_fma(V2, V2, sv4);
        sv4 = __builtin_elementwise_fma(V3, V3, sv4);
        sv4 = __builtin_elementwise_fma(V4, V4, sv4);
        f32x4 rsu4, rsv4;
#define RSUR(r) { float s_ = su4[r]; RED16(s_); rsu4[r] = RSQ(fmaf(s_, 0.0125f, EPSC)); \
                  float t_ = sv4[r]; RED16(t_); rsv4[r] = RSQ(fmaf(t_, 0.0125f, EPSC)); }
        RSUR(0) RSUR(1) RSUR(2) RSUR(3)

        const int gibase = blockIdx.x * 256 + wv * 64 + af * 16;
        // fused per-coordinate epilogue: lane owns unit c16 (gates t0..3 lane-local)
#define EPI(r) { \
    float z0_ = fmaf(U0[r] * ct0[0], rsu4[r], fmaf(V0[r] * ct0[1], rsv4[r], ct0[2])); \
    float z1_ = fmaf(U1[r] * ct1[0], rsu4[r], fmaf(V1[r] * ct1[1], rsv4[r], ct1[2])); \
    float z2_ = fmaf(U2[r] * ct2[0], rsu4[r], fmaf(V2[r] * ct2[1], rsv4[r], ct2[2])); \
    float z3_ = fmaf(U3[r] * ct3[0], rsu4[r], fmaf(V3[r] * ct3[1], rsv4[r], ct3[2])); \
    float z4_ = fmaf(U4[r] * ct4[0], rsu4[r], fmaf(V4[r] * ct4[1], rsv4[r], ct4[2])); \
    float wi_ = RCP(1.f + EXP2(z0_)); \
    float wf_ = RCP(1.f + EXP2(z1_)); \
    float wg_ = fmaf(-2.f, RCP(1.f + EXP2(z2_)), 1.f); \
    float wo_ = RCP(1.f + EXP2(z3_)); \
    float w4_ = fmaf(b4, RCP(1.f + EXP2(z4_)), a4); \
    float wi4_ = DPPF(w4_, 0x00), wf4_ = DPPF(w4_, 0x55); \
    float wg4_ = DPPF(w4_, 0xAA), wo4_ = DPPF(w4_, 0xFF); \
    float c0m_ = bfu(((u32)c0m2[(r) >> 1] >> (((r) & 1) * 16)) & 0xffffu); \
    float c0t_ = bfu(((u32)c0t2[(r) >> 1] >> (((r) & 1) * 16)) & 0xffffu); \
    float c1m_ = fmaf(wf_, c0m_, wi_ * wg_); \
    float c1t_ = fmaf(wf4_, c0t_, wi4_ * wg4_); \
    float s1_ = fmaf(0.25f, c1t_, c1m_); RED16(s1_); \
    float s2_ = fmaf(c1t_ * 0.25f, c1t_, c1m_ * c1m_); RED16(s2_); \
    float mu_ = s1_ * 0.05f; \
    float rsc_ = RSQ(fmaf(s2_, 0.05f, -mu_ * mu_) + EPSC); \
    float tnm_ = TANH2(fmaf((c1m_ - mu_) * rsc_, km[0], km[1])); \
    float tnt_ = TANH2(fmaf((c1t_ - mu_) * rsc_, k4[0], k4[1])); \
    float o_ = fmaf(wo_ * tnm_, km[2], wo4_ * tnt_ * k4[2]); \
    RED16(o_); \
    if (c16 == (r)) { int gi_ = gibase + hi * 4 + (r); \
        if (gi_ < n) out[gi_] = o_ + bo_; } }
        EPI(0) EPI(1) EPI(2) EPI(3)
    }
}

extern "C" void kernel_launch(void* const* d_in, const int* in_sizes, int n_in,
                              void* d_out, int out_size, void* d_ws, size_t ws_size,
                              hipStream_t stream) {
    const float* x_t  = (const float*)d_in[0];
    const float* W1   = (const float*)d_in[1];
    const float* b1   = (const float*)d_in[2];
    const float* Wih  = (const float*)d_in[3];
    const float* Whh  = (const float*)d_in[4];
    const float* b_ih = (const float*)d_in[5];
    const float* b_hh = (const float*)d_in[6];
    const float* g_x  = (const float*)d_in[7];
    const float* be_x = (const float*)d_in[8];
    const float* g_h  = (const float*)d_in[9];
    const float* be_h = (const float*)d_in[10];
    const float* g_c  = (const float*)d_in[11];
    const float* be_c = (const float*)d_in[12];
    const float* Wo   = (const float*)d_in[13];
    const float* bo   = (const float*)d_in[14];
    float* out = (float*)d_out;
    float* ws  = (float*)d_ws;
    const int n = in_sizes[0];

    hipLaunchKernelGGL(ml_precompute, dim3(1), dim3(256), 0, stream,
                       W1, b1, Wih, Whh, b_ih, b_hh, g_x, be_x, g_h, be_h,
                       g_c, be_c, Wo, bo, ws);
    const int blocks = (n + 255) / 256;
    hipLaunchKernelGGL(ml_main, dim3(blocks), dim3(256), 0, stream,
                       x_t, ws, out, n);
}

// Round 10
// 81.425 us; speedup vs baseline: 2.0930x; 1.1490x over previous
//
#include <hip/hip_runtime.h>

#define HN 20
#define G4 80
#define EPSC 1e-5f
#define L2E 1.4426950408889634f
#define TABN 16384
#define TAB_OFF 4608   // float offset of table in ws

typedef float v2f __attribute__((ext_vector_type(2)));
typedef float f32x4 __attribute__((ext_vector_type(4)));
typedef short short8 __attribute__((ext_vector_type(8)));
typedef int i32x4 __attribute__((ext_vector_type(4)));
typedef int i32x2 __attribute__((ext_vector_type(2)));
typedef unsigned int u32;

#if __has_builtin(__builtin_amdgcn_exp2f)
#define EXP2(x) __builtin_amdgcn_exp2f(x)
#else
#define EXP2(x) __expf((x) * 0.6931471805599453f)
#endif
#define RCP(x) __builtin_amdgcn_rcpf(x)
#define RSQ(x) __builtin_amdgcn_rsqf(x)
#define SIG2(z) RCP(1.f + EXP2(z))                   // z pre-scaled by -L2E
#define TANH2(z) fmaf(-2.f, RCP(1.f + EXP2(z)), 1.f) // z pre-scaled by +2*L2E

__device__ __forceinline__ u32 bfr(float f) { return (__float_as_uint(f) + 0x8000u) >> 16; }
__device__ __forceinline__ float bfu(u32 b) { return __uint_as_float(b << 16); }

#define REP20(M) M(0) M(1) M(2) M(3) M(4) M(5) M(6) M(7) M(8) M(9) \
                 M(10) M(11) M(12) M(13) M(14) M(15) M(16) M(17) M(18) M(19)

// shared layer-0 closed-form macros (scalar x -> c0_k, h_k)
#define L0A(k) float c0_##k; {                                              \
    float zi_ = fmaf(fmaf(Ag[k], x, Cg[k]), rs0, K0[k]);                    \
    float zg_ = fmaf(fmaf(Ag[40 + k], x, Cg[40 + k]), rs0, K0[40 + k]);     \
    c0_##k = SIG2(zi_) * TANH2(zg_);                                        \
    mu += c0_##k; m2 = fmaf(c0_##k, c0_##k, m2); }
#define L0B(k) float h_##k; {                                               \
    float zo_ = fmaf(fmaf(Ag[60 + k], x, Cg[60 + k]), rs0, K0[60 + k]);     \
    float tn_ = TANH2(fmaf((c0_##k - mu) * rsc, sg0[k], sb0[k]));           \
    h_##k = SIG2(zo_) * tn_; }

// ws layout (floats):
//   [0..79] Ag  [80..159] Cg  [160..239] K0     (layer-0, exp2-prescaled)
//   [240..242] va, cov, vc
//   [256..575]  colTab: 80 x f32x4 {GS, GH, K1s, ab}   (entry 16*tau + c)
//   [576..639]  kTab main: 16 x f32x4 {sgc1, sbc1, Wo[c], 0}
//   [640..703]  kTab4:     16 x f32x4 {sgc1[u], sbc1[u], Wo[u]/4, 0}, u=16+(c>>2)
//   [704..3263] Bfrag: 5120 bf16 = 10 tiles x 64 lanes x 8 elems
//   [4336..4355] sgc0  [4356..4375] sbc0        (layer-0 c-LN, 2L2E-scaled)
//   [4436] bo
//   [4608 ...]  layer-0 table: TABN x 128 B {h[32] bf16 (20..31=0), c0[20] bf16, pad}
__global__ void ml_precompute(
    const float* __restrict__ W1, const float* __restrict__ b1,
    const float* __restrict__ Wih, const float* __restrict__ Whh,
    const float* __restrict__ b_ih, const float* __restrict__ b_hh,
    const float* __restrict__ g_x, const float* __restrict__ be_x,
    const float* __restrict__ g_h, const float* __restrict__ be_h,
    const float* __restrict__ g_c, const float* __restrict__ be_c,
    const float* __restrict__ Wo, const float* __restrict__ bo,
    float* __restrict__ ws)
{
    __shared__ float A[G4], C[G4];
    __shared__ float cm[2][HN];
    __shared__ float stats[3];
    __shared__ float Wc[1600], Vc[1600];
    const int t = threadIdx.x;

    if (t < G4) {
        float a = 0.f, c = 0.f;
        for (int k = 0; k < HN; ++k) {
            float w = Wih[t * HN + k];
            a += w * W1[k];
            c += w * b1[k];
        }
        A[t] = a; C[t] = c;
    }
    if (t >= 128 && t < 128 + 2 * HN) {
        int k = (t - 128) % HN;
        const float* src = ((t - 128) < HN) ? (Wih + 1600) : (Whh + 1600);
        float s = 0.f;
        for (int j = 0; j < G4; ++j) s += src[j * HN + k];
        cm[(t - 128) / HN][k] = s * (1.f / 80.f);
    }
    __syncthreads();

    for (int idx = t; idx < 1600; idx += blockDim.x) {
        int k = idx % HN;
        Wc[idx] = Wih[1600 + idx] - cm[0][k];
        Vc[idx] = Whh[1600 + idx] - cm[1][k];
    }
    if (t == 0) {
        float am = 0.f, c_m = 0.f;
        for (int j = 0; j < G4; ++j) { am += A[j]; c_m += C[j]; }
        am *= (1.f / 80.f); c_m *= (1.f / 80.f);
        float va = 0.f, cov = 0.f, vc = 0.f;
        for (int j = 0; j < G4; ++j) {
            float ah = A[j] - am, ch = C[j] - c_m;
            va += ah * ah; cov += ah * ch; vc += ch * ch;
            A[j] = ah; C[j] = ch;
        }
        stats[0] = va * (1.f / 80.f);
        stats[1] = cov * (1.f / 80.f);
        stats[2] = vc * (1.f / 80.f);
    }
    __syncthreads();

    // layer-0 constants (exp2-prescaled, sigmoid sign folded)
    if (t < G4) {
        float sc = (t >= 40 && t < 60) ? (2.f * L2E) : (-L2E);
        ws[t]       = A[t] * g_x[t] * sc;
        ws[80 + t]  = C[t] * g_x[t] * sc;
        ws[160 + t] = (be_x[t] + be_h[t] + b_ih[t] + b_hh[t]) * sc;
    }
    if (t < 3) ws[240 + t] = stats[t];
    if (t < HN) {
        ws[4336 + t] = g_c[t] * (2.f * L2E);
        ws[4356 + t] = be_c[t] * (2.f * L2E);
    }
    if (t == 0) ws[4436] = bo[0];

    // colTab: entry t = 16*tau + c
    if (t < G4) {
        int tau = t >> 4, c = t & 15;
        int g, u;
        if (tau < 4) { g = tau; u = c; }
        else         { g = c & 3; u = 16 + (c >> 2); }
        int row = g * 20 + u;
        float sc = (g == 2) ? (2.f * L2E) : (-L2E);
        float k1 = be_x[80 + row] + be_h[80 + row] + b_ih[80 + row] + b_hh[80 + row]
                 + ((g == 1) ? 1.f : 0.f);
        float aa = (g == 2) ? 1.f : 0.f;
        float bb = (g == 2) ? -2.f : 1.f;
        ws[256 + 4 * t + 0] = g_x[80 + row] * sc;
        ws[256 + 4 * t + 1] = g_h[80 + row] * sc;
        ws[256 + 4 * t + 2] = k1 * sc;
        ws[256 + 4 * t + 3] = __uint_as_float(bfr(aa) | (bfr(bb) << 16));
    }
    if (t < 16) {
        ws[576 + 4 * t + 0] = g_c[HN + t] * (2.f * L2E);
        ws[576 + 4 * t + 1] = be_c[HN + t] * (2.f * L2E);
        ws[576 + 4 * t + 2] = Wo[t];
        ws[576 + 4 * t + 3] = 0.f;
    }
    if (t >= 16 && t < 32) {
        int c = t - 16, u = 16 + (c >> 2);
        ws[640 + 4 * c + 0] = g_c[HN + u] * (2.f * L2E);
        ws[640 + 4 * c + 1] = be_c[HN + u] * (2.f * L2E);
        ws[640 + 4 * c + 2] = Wo[u] * 0.25f;
        ws[640 + 4 * c + 3] = 0.f;
    }
    // B fragments
    {
        unsigned short* bf = (unsigned short*)(ws + 704);
        for (int e = t; e < 5120; e += blockDim.x) {
            int tt = e >> 9;
            int l = (e >> 3) & 63;
            int j = e & 7;
            int k = ((l >> 4) << 3) + j;
            int c = l & 15, tau = tt % 5;
            int g, u;
            if (tau < 4) { g = tau; u = c; }
            else         { g = c & 3; u = 16 + (c >> 2); }
            const float* src = (tt < 5) ? Wc : Vc;
            float val = (k < HN) ? src[(g * 20 + u) * HN + k] : 0.f;
            bf[e] = (unsigned short)bfr(val);
        }
    }
}

// ---------------- layer-0 table builder (grid-wide, after ml_precompute) ---
__global__ void ml_table(float* __restrict__ ws)
{
    const int idx = blockIdx.x * blockDim.x + threadIdx.x;
    if (idx >= TABN) return;
    const float x = (float)(idx - TABN / 2) * (16.f / (float)TABN);

    const float* Ag = ws;
    const float* Cg = ws + 80;
    const float* K0 = ws + 160;
    const float* sg0 = ws + 4336;
    const float* sb0 = ws + 4356;
    const float va = ws[240], cov = ws[241], vc = ws[242];
    const float rs0 = RSQ(fmaf(va * x, x, fmaf(2.f * cov, x, vc)) + EPSC);

    float mu = 0.f, m2 = 0.f;
    REP20(L0A)
    mu *= 0.05f;
    const float rsc = RSQ(fmaf(m2, 0.05f, -mu * mu) + EPSC);
    REP20(L0B)

    u32* ent = (u32*)((char*)(ws + TAB_OFF) + (size_t)idx * 128);
#define PKH(a,b) (bfr(h_##a) | (bfr(h_##b) << 16))
#define PKC(a,b) (bfr(c0_##a) | (bfr(c0_##b) << 16))
    i32x4 w0; w0[0] = PKH(0,1);  w0[1] = PKH(2,3);   w0[2] = PKH(4,5);   w0[3] = PKH(6,7);
    i32x4 w1; w1[0] = PKH(8,9);  w1[1] = PKH(10,11); w1[2] = PKH(12,13); w1[3] = PKH(14,15);
    i32x4 w2; w2[0] = PKH(16,17); w2[1] = PKH(18,19); w2[2] = 0; w2[3] = 0;
    i32x4 w3; w3[0] = 0; w3[1] = 0; w3[2] = 0; w3[3] = 0;
    i32x4 w4; w4[0] = PKC(0,1);  w4[1] = PKC(2,3);   w4[2] = PKC(4,5);   w4[3] = PKC(6,7);
    i32x4 w5; w5[0] = PKC(8,9);  w5[1] = PKC(10,11); w5[2] = PKC(12,13); w5[3] = PKC(14,15);
    i32x4 w6; w6[0] = PKC(16,17); w6[1] = PKC(18,19); w6[2] = 0; w6[3] = 0;
    ((i32x4*)ent)[0] = w0; ((i32x4*)ent)[1] = w1;
    ((i32x4*)ent)[2] = w2; ((i32x4*)ent)[3] = w3;
    ((i32x4*)ent)[4] = w4; ((i32x4*)ent)[5] = w5;
    ((i32x4*)ent)[6] = w6; ((i32x4*)ent)[7] = w3;
}

// ------------------------------ main kernel --------------------------------
#define DPPF(x, ctrl) __int_as_float(__builtin_amdgcn_mov_dpp(__float_as_int(x), (ctrl), 0xf, 0xf, true))
#define RED16(s) do { s += DPPF(s, 0x128); s += DPPF(s, 0x124); \
                      s += DPPF(s, 0x122); s += DPPF(s, 0x121); } while (0)

template<int MODE>  // 0 = table-driven layer 0, 1 = inline layer 0 (fallback)
__global__ __launch_bounds__(256, 3) void ml_main(
    const float* __restrict__ x_t,
    const float* __restrict__ ws,
    float* __restrict__ out, int n)
{
    __shared__ __align__(16) unsigned short At[4][64 * 40];  // [wave][coord][40] (k<32)
    __shared__ __align__(16) unsigned short C0R[4][64][24];  // c0 row-major: [wave][coord][unit]
    __shared__ f32x4 LT[112];
    const int tid = threadIdx.x, wv = tid >> 6, l = tid & 63;

    if (tid < 112) LT[tid] = ((const f32x4*)(ws + 256))[tid];

    // B fragments: 10 coalesced 16B loads per lane
    const short8* __restrict__ bfp = (const short8*)(ws + 704);
    short8 B0 = bfp[0 * 64 + l], B1 = bfp[1 * 64 + l], B2 = bfp[2 * 64 + l],
           B3 = bfp[3 * 64 + l], B4 = bfp[4 * 64 + l], B5 = bfp[5 * 64 + l],
           B6 = bfp[6 * 64 + l], B7 = bfp[7 * 64 + l], B8 = bfp[8 * 64 + l],
           B9 = bfp[9 * 64 + l];

    // ---- phase 1: layer 0 ----
    const int gi0 = blockIdx.x * 256 + tid;
    const float x = (gi0 < n) ? x_t[gi0] : 0.f;

    if constexpr (MODE == 0) {
        int idx = (int)fmaf(x, (float)TABN / 16.f, (float)(TABN / 2) + 0.5f);
        idx = idx < 0 ? 0 : (idx > TABN - 1 ? TABN - 1 : idx);
        const i32x4* ent = (const i32x4*)((const char*)(ws + TAB_OFF) + (size_t)idx * 128);
        i32x4 e0 = ent[0], e1 = ent[1], e2 = ent[2], e3 = ent[3];
        i32x4 e4 = ent[4], e5 = ent[5];
        i32x2 e6 = *(const i32x2*)((const u32*)ent + 24);
        unsigned short* arow = &At[wv][l * 40];
        *(i32x4*)(arow + 0)  = e0;
        *(i32x4*)(arow + 8)  = e1;
        *(i32x4*)(arow + 16) = e2;
        *(i32x4*)(arow + 24) = e3;
        unsigned short* crow = &C0R[wv][l][0];
        *(i32x4*)(crow + 0)  = e4;
        *(i32x4*)(crow + 8)  = e5;
        *(i32x2*)(crow + 16) = e6;
    } else {
        const float* Ag = ws;
        const float* Cg = ws + 80;
        const float* K0 = ws + 160;
        const float* sg0 = ws + 4336;
        const float* sb0 = ws + 4356;
        const float va = ws[240], cov = ws[241], vc = ws[242];
        const float rs0 = RSQ(fmaf(va * x, x, fmaf(2.f * cov, x, vc)) + EPSC);
        float mu = 0.f, m2 = 0.f;
        REP20(L0A)
        mu *= 0.05f;
        const float rsc = RSQ(fmaf(m2, 0.05f, -mu * mu) + EPSC);
        REP20(L0B)
        unsigned short* arow = &At[wv][l * 40];
        i32x4 aw0; aw0[0] = PKH(0,1); aw0[1] = PKH(2,3); aw0[2] = PKH(4,5); aw0[3] = PKH(6,7);
        i32x4 aw1; aw1[0] = PKH(8,9); aw1[1] = PKH(10,11); aw1[2] = PKH(12,13); aw1[3] = PKH(14,15);
        i32x4 aw2; aw2[0] = PKH(16,17); aw2[1] = PKH(18,19); aw2[2] = 0; aw2[3] = 0;
        *(i32x4*)(arow + 0)  = aw0;
        *(i32x4*)(arow + 8)  = aw1;
        *(i32x4*)(arow + 16) = aw2;
        i32x4 cw0; cw0[0] = PKC(0,1); cw0[1] = PKC(2,3); cw0[2] = PKC(4,5); cw0[3] = PKC(6,7);
        i32x4 cw1; cw1[0] = PKC(8,9); cw1[1] = PKC(10,11); cw1[2] = PKC(12,13); cw1[3] = PKC(14,15);
        i32x2 cw2; cw2[0] = PKC(16,17); cw2[1] = PKC(18,19);
        unsigned short* crow = &C0R[wv][l][0];
        *(i32x4*)(crow + 0)  = cw0;
        *(i32x4*)(crow + 8)  = cw1;
        *(i32x2*)(crow + 16) = cw2;
    }
    __syncthreads();

    // ---- phase 3: MFMA + lane-owns-unit epilogue (identical to round 9) ----
    const int c16 = l & 15, hi = l >> 4, q = c16 >> 2;
    const f32x4 ct0 = LT[c16],      ct1 = LT[16 + c16], ct2 = LT[32 + c16],
                ct3 = LT[48 + c16], ct4 = LT[64 + c16];
    const f32x4 km = LT[80 + c16], k4 = LT[96 + c16];
    const u32 ab4 = __float_as_uint(ct4[3]);
    const float a4 = bfu(ab4 & 0xffffu), b4 = bfu(ab4 >> 16);
    const float bo_ = ws[4436];

    for (int af = 0; af < 4; ++af) {
        short8 a8 = *(const short8*)&At[wv][(af * 16 + c16) * 40 + hi * 8];
        f32x4 z4; z4[0] = 0.f; z4[1] = 0.f; z4[2] = 0.f; z4[3] = 0.f;
        f32x4 U0 = __builtin_amdgcn_mfma_f32_16x16x32_bf16(a8, B0, z4, 0, 0, 0);
        f32x4 U1 = __builtin_amdgcn_mfma_f32_16x16x32_bf16(a8, B1, z4, 0, 0, 0);
        f32x4 U2 = __builtin_amdgcn_mfma_f32_16x16x32_bf16(a8, B2, z4, 0, 0, 0);
        f32x4 U3 = __builtin_amdgcn_mfma_f32_16x16x32_bf16(a8, B3, z4, 0, 0, 0);
        f32x4 U4 = __builtin_amdgcn_mfma_f32_16x16x32_bf16(a8, B4, z4, 0, 0, 0);
        f32x4 V0 = __builtin_amdgcn_mfma_f32_16x16x32_bf16(a8, B5, z4, 0, 0, 0);
        f32x4 V1 = __builtin_amdgcn_mfma_f32_16x16x32_bf16(a8, B6, z4, 0, 0, 0);
        f32x4 V2 = __builtin_amdgcn_mfma_f32_16x16x32_bf16(a8, B7, z4, 0, 0, 0);
        f32x4 V3 = __builtin_amdgcn_mfma_f32_16x16x32_bf16(a8, B8, z4, 0, 0, 0);
        f32x4 V4 = __builtin_amdgcn_mfma_f32_16x16x32_bf16(a8, B9, z4, 0, 0, 0);

        f32x4 su4 = U0 * U0;
        su4 = __builtin_elementwise_fma(U1, U1, su4);
        su4 = __builtin_elementwise_fma(U2, U2, su4);
        su4 = __builtin_elementwise_fma(U3, U3, su4);
        su4 = __builtin_elementwise_fma(U4, U4, su4);
        f32x4 sv4 = V0 * V0;
        sv4 = __builtin_elementwise_fma(V1, V1, sv4);
        sv4 = __builtin_elementwise_fma(V2, V2, sv4);
        sv4 = __builtin_elementwise_fma(V3, V3, sv4);
        sv4 = __builtin_elementwise_fma(V4, V4, sv4);
        f32x4 rsu4, rsv4;
#define RSUR(r) { float s_ = su4[r]; RED16(s_); rsu4[r] = RSQ(fmaf(s_, 0.0125f, EPSC)); \
                  float t_ = sv4[r]; RED16(t_); rsv4[r] = RSQ(fmaf(t_, 0.0125f, EPSC)); }
        RSUR(0) RSUR(1) RSUR(2) RSUR(3)

        const int gibase = blockIdx.x * 256 + wv * 64 + af * 16;
#define EPI(r) { \
    float z0_ = fmaf(U0[r] * ct0[0], rsu4[r], fmaf(V0[r] * ct0[1], rsv4[r], ct0[2])); \
    float z1_ = fmaf(U1[r] * ct1[0], rsu4[r], fmaf(V1[r] * ct1[1], rsv4[r], ct1[2])); \
    float z2_ = fmaf(U2[r] * ct2[0], rsu4[r], fmaf(V2[r] * ct2[1], rsv4[r], ct2[2])); \
    float z3_ = fmaf(U3[r] * ct3[0], rsu4[r], fmaf(V3[r] * ct3[1], rsv4[r], ct3[2])); \
    float z4_ = fmaf(U4[r] * ct4[0], rsu4[r], fmaf(V4[r] * ct4[1], rsv4[r], ct4[2])); \
    float wi_ = RCP(1.f + EXP2(z0_)); \
    float wf_ = RCP(1.f + EXP2(z1_)); \
    float wg_ = fmaf(-2.f, RCP(1.f + EXP2(z2_)), 1.f); \
    float wo_ = RCP(1.f + EXP2(z3_)); \
    float w4_ = fmaf(b4, RCP(1.f + EXP2(z4_)), a4); \
    float wi4_ = DPPF(w4_, 0x00), wf4_ = DPPF(w4_, 0x55); \
    float wg4_ = DPPF(w4_, 0xAA), wo4_ = DPPF(w4_, 0xFF); \
    float c0m_ = bfu((u32)C0R[wv][af * 16 + hi * 4 + (r)][c16]); \
    float c0t_ = bfu((u32)C0R[wv][af * 16 + hi * 4 + (r)][16 + q]); \
    float c1m_ = fmaf(wf_, c0m_, wi_ * wg_); \
    float c1t_ = fmaf(wf4_, c0t_, wi4_ * wg4_); \
    float s1_ = fmaf(0.25f, c1t_, c1m_); RED16(s1_); \
    float s2_ = fmaf(c1t_ * 0.25f, c1t_, c1m_ * c1m_); RED16(s2_); \
    float mu_ = s1_ * 0.05f; \
    float rsc_ = RSQ(fmaf(s2_, 0.05f, -mu_ * mu_) + EPSC); \
    float tnm_ = TANH2(fmaf((c1m_ - mu_) * rsc_, km[0], km[1])); \
    float tnt_ = TANH2(fmaf((c1t_ - mu_) * rsc_, k4[0], k4[1])); \
    float o_ = fmaf(wo_ * tnm_, km[2], wo4_ * tnt_ * k4[2]); \
    RED16(o_); \
    if (c16 == (r)) { int gi_ = gibase + hi * 4 + (r); \
        if (gi_ < n) out[gi_] = o_ + bo_; } }
        EPI(0) EPI(1) EPI(2) EPI(3)
    }
}

extern "C" void kernel_launch(void* const* d_in, const int* in_sizes, int n_in,
                              void* d_out, int out_size, void* d_ws, size_t ws_size,
                              hipStream_t stream) {
    const float* x_t  = (const float*)d_in[0];
    const float* W1   = (const float*)d_in[1];
    const float* b1   = (const float*)d_in[2];
    const float* Wih  = (const float*)d_in[3];
    const float* Whh  = (const float*)d_in[4];
    const float* b_ih = (const float*)d_in[5];
    const float* b_hh = (const float*)d_in[6];
    const float* g_x  = (const float*)d_in[7];
    const float* be_x = (const float*)d_in[8];
    const float* g_h  = (const float*)d_in[9];
    const float* be_h = (const float*)d_in[10];
    const float* g_c  = (const float*)d_in[11];
    const float* be_c = (const float*)d_in[12];
    const float* Wo   = (const float*)d_in[13];
    const float* bo   = (const float*)d_in[14];
    float* out = (float*)d_out;
    float* ws  = (float*)d_ws;
    const int n = in_sizes[0];

    hipLaunchKernelGGL(ml_precompute, dim3(1), dim3(256), 0, stream,
                       W1, b1, Wih, Whh, b_ih, b_hh, g_x, be_x, g_h, be_h,
                       g_c, be_c, Wo, bo, ws);
    const int blocks = (n + 255) / 256;
    const size_t need = (size_t)TAB_OFF * 4 + (size_t)TABN * 128;
    if (ws_size >= need) {
        hipLaunchKernelGGL(ml_table, dim3(TABN / 256), dim3(256), 0, stream, ws);
        hipLaunchKernelGGL(ml_main<0>, dim3(blocks), dim3(256), 0, stream,
                           x_t, ws, out, n);
    } else {
        hipLaunchKernelGGL(ml_main<1>, dim3(blocks), dim3(256), 0, stream,
                           x_t, ws, out, n);
    }
}

// Round 13
// 29.078 us; speedup vs baseline: 5.8608x; 2.8003x over previous
//
#include <hip/hip_runtime.h>

#define HN 20
#define G4 80
#define EPSC 1e-5f
#define L2E 1.4426950408889634f
#define FT_N 32768     // F-table entries over x in [-8, 8), step 1/2048
#define FT_OFF 8192    // float offset of F-table in ws

typedef float v2f __attribute__((ext_vector_type(2)));
typedef float f32x4 __attribute__((ext_vector_type(4)));
typedef short short8 __attribute__((ext_vector_type(8)));
typedef int i32x4 __attribute__((ext_vector_type(4)));
typedef int i32x2 __attribute__((ext_vector_type(2)));
typedef unsigned int u32;

#if __has_builtin(__builtin_amdgcn_exp2f)
#define EXP2(x) __builtin_amdgcn_exp2f(x)
#else
#define EXP2(x) __expf((x) * 0.6931471805599453f)
#endif
#define RCP(x) __builtin_amdgcn_rcpf(x)
#define RSQ(x) __builtin_amdgcn_rsqf(x)
#define SIG2(z) RCP(1.f + EXP2(z))                   // z pre-scaled by -L2E
#define TANH2(z) fmaf(-2.f, RCP(1.f + EXP2(z)), 1.f) // z pre-scaled by +2*L2E

__device__ __forceinline__ u32 bfr(float f) { return (__float_as_uint(f) + 0x8000u) >> 16; }
__device__ __forceinline__ float bfu(u32 b) { return __uint_as_float(b << 16); }

#define REP20(M) M(0) M(1) M(2) M(3) M(4) M(5) M(6) M(7) M(8) M(9) \
                 M(10) M(11) M(12) M(13) M(14) M(15) M(16) M(17) M(18) M(19)

// layer-0 closed-form macros (scalar x -> c0_k, h_k)
#define L0A(k) float c0_##k; {                                              \
    float zi_ = fmaf(fmaf(Ag[k], x, Cg[k]), rs0, K0[k]);                    \
    float zg_ = fmaf(fmaf(Ag[40 + k], x, Cg[40 + k]), rs0, K0[40 + k]);     \
    c0_##k = SIG2(zi_) * TANH2(zg_);                                        \
    mu += c0_##k; m2 = fmaf(c0_##k, c0_##k, m2); }
#define L0B(k) float h_##k; {                                               \
    float zo_ = fmaf(fmaf(Ag[60 + k], x, Cg[60 + k]), rs0, K0[60 + k]);     \
    float tn_ = TANH2(fmaf((c0_##k - mu) * rsc, sg0[k], sb0[k]));           \
    h_##k = SIG2(zo_) * tn_; }
#define PKH(a,b) ((int)(bfr(h_##a) | (bfr(h_##b) << 16)))
#define PKC(a,b) ((int)(bfr(c0_##a) | (bfr(c0_##b) << 16)))

// ws layout (floats):
//   [0..79] Ag  [80..159] Cg  [160..239] K0     (layer-0, exp2-prescaled)
//   [240..242] va, cov, vc
//   [256..575]  colTab: 80 x f32x4 {GS, GH, K1s, ab}   (entry 16*tau + c)
//   [576..639]  kTab main: 16 x f32x4 {sgc1, sbc1, Wo[c], 0}
//   [640..703]  kTab4:     16 x f32x4 {sgc1[u], sbc1[u], Wo[u]/4, 0}, u=16+(c>>2)
//   [704..3263] Bfrag: 5120 bf16 = 10 tiles x 64 lanes x 8 elems
//   [4336..4355] sgc0  [4356..4375] sbc0        (layer-0 c-LN, 2L2E-scaled)
//   [4436] bo
//   [8192..40959] F-table: FT_N floats, F((i-16384)/2048)
__global__ void ml_precompute(
    const float* __restrict__ W1, const float* __restrict__ b1,
    const float* __restrict__ Wih, const float* __restrict__ Whh,
    const float* __restrict__ b_ih, const float* __restrict__ b_hh,
    const float* __restrict__ g_x, const float* __restrict__ be_x,
    const float* __restrict__ g_h, const float* __restrict__ be_h,
    const float* __restrict__ g_c, const float* __restrict__ be_c,
    const float* __restrict__ Wo, const float* __restrict__ bo,
    float* __restrict__ ws)
{
    __shared__ float A[G4], C[G4];
    __shared__ float cm[2][HN];
    __shared__ float stats[3];
    __shared__ float Wc[1600], Vc[1600];
    const int t = threadIdx.x;

    if (t < G4) {
        float a = 0.f, c = 0.f;
        for (int k = 0; k < HN; ++k) {
            float w = Wih[t * HN + k];
            a += w * W1[k];
            c += w * b1[k];
        }
        A[t] = a; C[t] = c;
    }
    if (t >= 128 && t < 128 + 2 * HN) {
        int k = (t - 128) % HN;
        const float* src = ((t - 128) < HN) ? (Wih + 1600) : (Whh + 1600);
        float s = 0.f;
        for (int j = 0; j < G4; ++j) s += src[j * HN + k];
        cm[(t - 128) / HN][k] = s * (1.f / 80.f);
    }
    __syncthreads();

    for (int idx = t; idx < 1600; idx += blockDim.x) {
        int k = idx % HN;
        Wc[idx] = Wih[1600 + idx] - cm[0][k];
        Vc[idx] = Whh[1600 + idx] - cm[1][k];
    }
    if (t == 0) {
        float am = 0.f, c_m = 0.f;
        for (int j = 0; j < G4; ++j) { am += A[j]; c_m += C[j]; }
        am *= (1.f / 80.f); c_m *= (1.f / 80.f);
        float va = 0.f, cov = 0.f, vc = 0.f;
        for (int j = 0; j < G4; ++j) {
            float ah = A[j] - am, ch = C[j] - c_m;
            va += ah * ah; cov += ah * ch; vc += ch * ch;
            A[j] = ah; C[j] = ch;
        }
        stats[0] = va * (1.f / 80.f);
        stats[1] = cov * (1.f / 80.f);
        stats[2] = vc * (1.f / 80.f);
    }
    __syncthreads();

    // layer-0 constants (exp2-prescaled, sigmoid sign folded)
    if (t < G4) {
        float sc = (t >= 40 && t < 60) ? (2.f * L2E) : (-L2E);
        ws[t]       = A[t] * g_x[t] * sc;
        ws[80 + t]  = C[t] * g_x[t] * sc;
        ws[160 + t] = (be_x[t] + be_h[t] + b_ih[t] + b_hh[t]) * sc;
    }
    if (t < 3) ws[240 + t] = stats[t];
    if (t < HN) {
        ws[4336 + t] = g_c[t] * (2.f * L2E);
        ws[4356 + t] = be_c[t] * (2.f * L2E);
    }
    if (t == 0) ws[4436] = bo[0];

    // colTab: entry t = 16*tau + c
    if (t < G4) {
        int tau = t >> 4, c = t & 15;
        int g, u;
        if (tau < 4) { g = tau; u = c; }
        else         { g = c & 3; u = 16 + (c >> 2); }
        int row = g * 20 + u;
        float sc = (g == 2) ? (2.f * L2E) : (-L2E);
        float k1 = be_x[80 + row] + be_h[80 + row] + b_ih[80 + row] + b_hh[80 + row]
                 + ((g == 1) ? 1.f : 0.f);
        float aa = (g == 2) ? 1.f : 0.f;
        float bb = (g == 2) ? -2.f : 1.f;
        ws[256 + 4 * t + 0] = g_x[80 + row] * sc;
        ws[256 + 4 * t + 1] = g_h[80 + row] * sc;
        ws[256 + 4 * t + 2] = k1 * sc;
        ws[256 + 4 * t + 3] = __uint_as_float(bfr(aa) | (bfr(bb) << 16));
    }
    if (t < 16) {
        ws[576 + 4 * t + 0] = g_c[HN + t] * (2.f * L2E);
        ws[576 + 4 * t + 1] = be_c[HN + t] * (2.f * L2E);
        ws[576 + 4 * t + 2] = Wo[t];
        ws[576 + 4 * t + 3] = 0.f;
    }
    if (t >= 16 && t < 32) {
        int c = t - 16, u = 16 + (c >> 2);
        ws[640 + 4 * c + 0] = g_c[HN + u] * (2.f * L2E);
        ws[640 + 4 * c + 1] = be_c[HN + u] * (2.f * L2E);
        ws[640 + 4 * c + 2] = Wo[u] * 0.25f;
        ws[640 + 4 * c + 3] = 0.f;
    }
    // B fragments
    {
        unsigned short* bf = (unsigned short*)(ws + 704);
        for (int e = t; e < 5120; e += blockDim.x) {
            int tt = e >> 9;
            int l = (e >> 3) & 63;
            int j = e & 7;
            int k = ((l >> 4) << 3) + j;
            int c = l & 15, tau = tt % 5;
            int g, u;
            if (tau < 4) { g = tau; u = c; }
            else         { g = c & 3; u = 16 + (c >> 2); }
            const float* src = (tt < 5) ? Wc : Vc;
            float val = (k < HN) ? src[(g * 20 + u) * HN + k] : 0.f;
            bf[e] = (unsigned short)bfr(val);
        }
    }
}

// ------------------------------ main kernel --------------------------------
#define DPPF(x, ctrl) __int_as_float(__builtin_amdgcn_mov_dpp(__float_as_int(x), (ctrl), 0xf, 0xf, true))
#define RED16(s) do { s += DPPF(s, 0x128); s += DPPF(s, 0x124); \
                      s += DPPF(s, 0x122); s += DPPF(s, 0x121); } while (0)

// MODE 1: x from x_t (full-N fallback). MODE 2: synthetic grid x (F-table build).
template<int MODE>
__global__ __launch_bounds__(256, 3) void ml_main(
    const float* __restrict__ x_t,
    const float* __restrict__ ws,
    float* out, int n)
{
    __shared__ __align__(16) unsigned short At[4][64 * 40];  // [wave][coord][40] (k<32)
    __shared__ __align__(16) unsigned short C0R[4][64][24];  // c0 row-major
    __shared__ f32x4 LT[112];
    const int tid = threadIdx.x, wv = tid >> 6, l = tid & 63;

    if (tid < 112) LT[tid] = ((const f32x4*)(ws + 256))[tid];

    const short8* __restrict__ bfp = (const short8*)(ws + 704);
    short8 B0 = bfp[0 * 64 + l], B1 = bfp[1 * 64 + l], B2 = bfp[2 * 64 + l],
           B3 = bfp[3 * 64 + l], B4 = bfp[4 * 64 + l], B5 = bfp[5 * 64 + l],
           B6 = bfp[6 * 64 + l], B7 = bfp[7 * 64 + l], B8 = bfp[8 * 64 + l],
           B9 = bfp[9 * 64 + l];

    // ---- phase 1: layer 0 (inline closed form) ----
    const int gi0 = blockIdx.x * 256 + tid;
    float x;
    if constexpr (MODE == 2) {
        x = (float)(gi0 - FT_N / 2) * (16.f / (float)FT_N);
    } else {
        x = (gi0 < n) ? x_t[gi0] : 0.f;
    }
    {
        const float* Ag = ws;
        const float* Cg = ws + 80;
        const float* K0 = ws + 160;
        const float* sg0 = ws + 4336;
        const float* sb0 = ws + 4356;
        const float va = ws[240], cov = ws[241], vc = ws[242];
        const float rs0 = RSQ(fmaf(va * x, x, fmaf(2.f * cov, x, vc)) + EPSC);
        float mu = 0.f, m2 = 0.f;
        REP20(L0A)
        mu *= 0.05f;
        const float rsc = RSQ(fmaf(m2, 0.05f, -mu * mu) + EPSC);
        REP20(L0B)
        unsigned short* arow = &At[wv][l * 40];
        i32x4 aw0; aw0[0] = PKH(0,1); aw0[1] = PKH(2,3); aw0[2] = PKH(4,5); aw0[3] = PKH(6,7);
        i32x4 aw1; aw1[0] = PKH(8,9); aw1[1] = PKH(10,11); aw1[2] = PKH(12,13); aw1[3] = PKH(14,15);
        i32x4 aw2; aw2[0] = PKH(16,17); aw2[1] = PKH(18,19); aw2[2] = 0; aw2[3] = 0;
        i32x4 zz4; zz4[0] = 0; zz4[1] = 0; zz4[2] = 0; zz4[3] = 0;
        *(i32x4*)(arow + 0)  = aw0;
        *(i32x4*)(arow + 8)  = aw1;
        *(i32x4*)(arow + 16) = aw2;
        *(i32x4*)(arow + 24) = zz4;   // BUGFIX: zero K-slots 24..31 (MFMA reads them)
        i32x4 cw0; cw0[0] = PKC(0,1); cw0[1] = PKC(2,3); cw0[2] = PKC(4,5); cw0[3] = PKC(6,7);
        i32x4 cw1; cw1[0] = PKC(8,9); cw1[1] = PKC(10,11); cw1[2] = PKC(12,13); cw1[3] = PKC(14,15);
        i32x2 cw2; cw2[0] = PKC(16,17); cw2[1] = PKC(18,19);
        unsigned short* crow = &C0R[wv][l][0];
        *(i32x4*)(crow + 0)  = cw0;
        *(i32x4*)(crow + 8)  = cw1;
        *(i32x2*)(crow + 16) = cw2;
    }
    __syncthreads();

    // ---- phase 3: MFMA + lane-owns-unit epilogue ----
    const int c16 = l & 15, hi = l >> 4, q = c16 >> 2;
    const f32x4 ct0 = LT[c16],      ct1 = LT[16 + c16], ct2 = LT[32 + c16],
                ct3 = LT[48 + c16], ct4 = LT[64 + c16];
    const f32x4 km = LT[80 + c16], k4 = LT[96 + c16];
    const u32 ab4 = __float_as_uint(ct4[3]);
    const float a4 = bfu(ab4 & 0xffffu), b4 = bfu(ab4 >> 16);
    const float bo_ = ws[4436];

    for (int af = 0; af < 4; ++af) {
        short8 a8 = *(const short8*)&At[wv][(af * 16 + c16) * 40 + hi * 8];
        f32x4 z4; z4[0] = 0.f; z4[1] = 0.f; z4[2] = 0.f; z4[3] = 0.f;
        f32x4 U0 = __builtin_amdgcn_mfma_f32_16x16x32_bf16(a8, B0, z4, 0, 0, 0);
        f32x4 U1 = __builtin_amdgcn_mfma_f32_16x16x32_bf16(a8, B1, z4, 0, 0, 0);
        f32x4 U2 = __builtin_amdgcn_mfma_f32_16x16x32_bf16(a8, B2, z4, 0, 0, 0);
        f32x4 U3 = __builtin_amdgcn_mfma_f32_16x16x32_bf16(a8, B3, z4, 0, 0, 0);
        f32x4 U4 = __builtin_amdgcn_mfma_f32_16x16x32_bf16(a8, B4, z4, 0, 0, 0);
        f32x4 V0 = __builtin_amdgcn_mfma_f32_16x16x32_bf16(a8, B5, z4, 0, 0, 0);
        f32x4 V1 = __builtin_amdgcn_mfma_f32_16x16x32_bf16(a8, B6, z4, 0, 0, 0);
        f32x4 V2 = __builtin_amdgcn_mfma_f32_16x16x32_bf16(a8, B7, z4, 0, 0, 0);
        f32x4 V3 = __builtin_amdgcn_mfma_f32_16x16x32_bf16(a8, B8, z4, 0, 0, 0);
        f32x4 V4 = __builtin_amdgcn_mfma_f32_16x16x32_bf16(a8, B9, z4, 0, 0, 0);

        f32x4 su4 = U0 * U0;
        su4 = __builtin_elementwise_fma(U1, U1, su4);
        su4 = __builtin_elementwise_fma(U2, U2, su4);
        su4 = __builtin_elementwise_fma(U3, U3, su4);
        su4 = __builtin_elementwise_fma(U4, U4, su4);
        f32x4 sv4 = V0 * V0;
        sv4 = __builtin_elementwise_fma(V1, V1, sv4);
        sv4 = __builtin_elementwise_fma(V2, V2, sv4);
        sv4 = __builtin_elementwise_fma(V3, V3, sv4);
        sv4 = __builtin_elementwise_fma(V4, V4, sv4);
        f32x4 rsu4, rsv4;
#define RSUR(r) { float s_ = su4[r]; RED16(s_); rsu4[r] = RSQ(fmaf(s_, 0.0125f, EPSC)); \
                  float t_ = sv4[r]; RED16(t_); rsv4[r] = RSQ(fmaf(t_, 0.0125f, EPSC)); }
        RSUR(0) RSUR(1) RSUR(2) RSUR(3)

        const int gibase = blockIdx.x * 256 + wv * 64 + af * 16;
#define EPI(r) { \
    float z0_ = fmaf(U0[r] * ct0[0], rsu4[r], fmaf(V0[r] * ct0[1], rsv4[r], ct0[2])); \
    float z1_ = fmaf(U1[r] * ct1[0], rsu4[r], fmaf(V1[r] * ct1[1], rsv4[r], ct1[2])); \
    float z2_ = fmaf(U2[r] * ct2[0], rsu4[r], fmaf(V2[r] * ct2[1], rsv4[r], ct2[2])); \
    float z3_ = fmaf(U3[r] * ct3[0], rsu4[r], fmaf(V3[r] * ct3[1], rsv4[r], ct3[2])); \
    float z4_ = fmaf(U4[r] * ct4[0], rsu4[r], fmaf(V4[r] * ct4[1], rsv4[r], ct4[2])); \
    float wi_ = RCP(1.f + EXP2(z0_)); \
    float wf_ = RCP(1.f + EXP2(z1_)); \
    float wg_ = fmaf(-2.f, RCP(1.f + EXP2(z2_)), 1.f); \
    float wo_ = RCP(1.f + EXP2(z3_)); \
    float w4_ = fmaf(b4, RCP(1.f + EXP2(z4_)), a4); \
    float wi4_ = DPPF(w4_, 0x00), wf4_ = DPPF(w4_, 0x55); \
    float wg4_ = DPPF(w4_, 0xAA), wo4_ = DPPF(w4_, 0xFF); \
    float c0m_ = bfu((u32)C0R[wv][af * 16 + hi * 4 + (r)][c16]); \
    float c0t_ = bfu((u32)C0R[wv][af * 16 + hi * 4 + (r)][16 + q]); \
    float c1m_ = fmaf(wf_, c0m_, wi_ * wg_); \
    float c1t_ = fmaf(wf4_, c0t_, wi4_ * wg4_); \
    float s1_ = fmaf(0.25f, c1t_, c1m_); RED16(s1_); \
    float s2_ = fmaf(c1t_ * 0.25f, c1t_, c1m_ * c1m_); RED16(s2_); \
    float mu_ = s1_ * 0.05f; \
    float rsc_ = RSQ(fmaf(s2_, 0.05f, -mu_ * mu_) + EPSC); \
    float tnm_ = TANH2(fmaf((c1m_ - mu_) * rsc_, km[0], km[1])); \
    float tnt_ = TANH2(fmaf((c1t_ - mu_) * rsc_, k4[0], k4[1])); \
    float o_ = fmaf(wo_ * tnm_, km[2], wo4_ * tnt_ * k4[2]); \
    RED16(o_); \
    if (c16 == (r)) { int gi_ = gibase + hi * 4 + (r); \
        if (gi_ < n) out[gi_] = o_ + bo_; } }
        EPI(0) EPI(1) EPI(2) EPI(3)
    }
}

// ---------------- final pass: out[i] = lerp(F-table, x[i]) -----------------
__global__ __launch_bounds__(256) void ml_apply(
    const float* __restrict__ x_t,
    const float* __restrict__ ftab,
    float* __restrict__ out, int n)
{
    const int g = blockIdx.x * 256 + threadIdx.x;
    const int base = g * 4;
    if (base + 4 <= n) {
        f32x4 xv = *(const f32x4*)(x_t + base);
        f32x4 ov;
#pragma unroll
        for (int j = 0; j < 4; ++j) {
            float xf = fmaf(xv[j], 2048.f, 16384.f);       // (x+8)*2048
            xf = fminf(fmaxf(xf, 0.f), (float)(FT_N - 2));
            float fl = floorf(xf);
            int idx = (int)fl;
            float fr = xf - fl;
            float a = ftab[idx], b = ftab[idx + 1];
            ov[j] = fmaf(fr, b - a, a);
        }
        *(f32x4*)(out + base) = ov;
    } else if (base < n) {
        for (int j = 0; j < n - base; ++j) {
            float xf = fmaf(x_t[base + j], 2048.f, 16384.f);
            xf = fminf(fmaxf(xf, 0.f), (float)(FT_N - 2));
            float fl = floorf(xf);
            int idx = (int)fl;
            float fr = xf - fl;
            float a = ftab[idx], b = ftab[idx + 1];
            out[base + j] = fmaf(fr, b - a, a);
        }
    }
}

extern "C" void kernel_launch(void* const* d_in, const int* in_sizes, int n_in,
                              void* d_out, int out_size, void* d_ws, size_t ws_size,
                              hipStream_t stream) {
    const float* x_t  = (const float*)d_in[0];
    const float* W1   = (const float*)d_in[1];
    const float* b1   = (const float*)d_in[2];
    const float* Wih  = (const float*)d_in[3];
    const float* Whh  = (const float*)d_in[4];
    const float* b_ih = (const float*)d_in[5];
    const float* b_hh = (const float*)d_in[6];
    const float* g_x  = (const float*)d_in[7];
    const float* be_x = (const float*)d_in[8];
    const float* g_h  = (const float*)d_in[9];
    const float* be_h = (const float*)d_in[10];
    const float* g_c  = (const float*)d_in[11];
    const float* be_c = (const float*)d_in[12];
    const float* Wo   = (const float*)d_in[13];
    const float* bo   = (const float*)d_in[14];
    float* out = (float*)d_out;
    float* ws  = (float*)d_ws;
    const int n = in_sizes[0];

    hipLaunchKernelGGL(ml_precompute, dim3(1), dim3(256), 0, stream,
                       W1, b1, Wih, Whh, b_ih, b_hh, g_x, be_x, g_h, be_h,
                       g_c, be_c, Wo, bo, ws);

    const size_t need = (size_t)(FT_OFF + FT_N) * 4;
    if (ws_size >= need) {
        // build F-table with the validated MFMA kernel, then lerp-apply
        hipLaunchKernelGGL(ml_main<2>, dim3(FT_N / 256), dim3(256), 0, stream,
                           x_t, ws, ws + FT_OFF, FT_N);
        const int g4 = (n + 3) / 4;
        hipLaunchKernelGGL(ml_apply, dim3((g4 + 255) / 256), dim3(256), 0, stream,
                           x_t, ws + FT_OFF, out, n);
    } else {
        const int blocks = (n + 255) / 256;
        hipLaunchKernelGGL(ml_main<1>, dim3(blocks), dim3(256), 0, stream,
                           x_t, ws, out, n);
    }
}

// Round 15
// 22.938 us; speedup vs baseline: 7.4296x; 1.2677x over previous
//
#include <hip/hip_runtime.h>

#define HN 20
#define G4 80
#define EPSC 1e-5f
#define L2E 1.4426950408889634f
#define FT_N 32768     // F-table entries over x in [-8, 8), step 1/2048

typedef float f32x4 __attribute__((ext_vector_type(4)));
typedef short short8 __attribute__((ext_vector_type(8)));
typedef int i32x4 __attribute__((ext_vector_type(4)));
typedef int i32x2 __attribute__((ext_vector_type(2)));
typedef unsigned int u32;

#if __has_builtin(__builtin_amdgcn_exp2f)
#define EXP2(x) __builtin_amdgcn_exp2f(x)
#else
#define EXP2(x) __expf((x) * 0.6931471805599453f)
#endif
#define RCP(x) __builtin_amdgcn_rcpf(x)
#define RSQ(x) __builtin_amdgcn_rsqf(x)
#define SIG2(z) RCP(1.f + EXP2(z))                   // z pre-scaled by -L2E
#define TANH2(z) fmaf(-2.f, RCP(1.f + EXP2(z)), 1.f) // z pre-scaled by +2*L2E

__device__ __forceinline__ u32 bfr(float f) { return (__float_as_uint(f) + 0x8000u) >> 16; }
__device__ __forceinline__ float bfu(u32 b) { return __uint_as_float(b << 16); }

#define REP20(M) M(0) M(1) M(2) M(3) M(4) M(5) M(6) M(7) M(8) M(9) \
                 M(10) M(11) M(12) M(13) M(14) M(15) M(16) M(17) M(18) M(19)

// layer-0 closed-form macros (scalar x -> c0_k, h_k); Ag/Cg/K0/sg0/sb0 = LDS ptrs
#define L0A(k) float c0_##k; {                                              \
    float zi_ = fmaf(fmaf(Ag[k], x, Cg[k]), rs0, K0[k]);                    \
    float zg_ = fmaf(fmaf(Ag[40 + k], x, Cg[40 + k]), rs0, K0[40 + k]);     \
    c0_##k = SIG2(zi_) * TANH2(zg_);                                        \
    mu += c0_##k; m2 = fmaf(c0_##k, c0_##k, m2); }
#define L0B(k) float h_##k; {                                               \
    float zo_ = fmaf(fmaf(Ag[60 + k], x, Cg[60 + k]), rs0, K0[60 + k]);     \
    float tn_ = TANH2(fmaf((c0_##k - mu) * rsc, sg0[k], sb0[k]));           \
    h_##k = SIG2(zo_) * tn_; }
#define PKH(a,b) ((int)(bfr(h_##a) | (bfr(h_##b) << 16)))
#define PKC(a,b) ((int)(bfr(c0_##a) | (bfr(c0_##b) << 16)))

#define DPPF(x, ctrl) __int_as_float(__builtin_amdgcn_mov_dpp(__float_as_int(x), (ctrl), 0xf, 0xf, true))
#define RED16(s) do { s += DPPF(s, 0x128); s += DPPF(s, 0x124); \
                      s += DPPF(s, 0x122); s += DPPF(s, 0x121); } while (0)

// B-fragment element: centered weight or 0 for k>=20 (clamped LDS address)
#define BVAL(SRC, RB, kk) (((kk) < HN) ? (SRC)[(RB) + (((kk) < HN) ? (kk) : 0)] : 0.f)
#define MKB(DST, SRC, RB) { \
    DST[0]=(short)bfr(BVAL(SRC,RB,k0+0)); DST[1]=(short)bfr(BVAL(SRC,RB,k0+1)); \
    DST[2]=(short)bfr(BVAL(SRC,RB,k0+2)); DST[3]=(short)bfr(BVAL(SRC,RB,k0+3)); \
    DST[4]=(short)bfr(BVAL(SRC,RB,k0+4)); DST[5]=(short)bfr(BVAL(SRC,RB,k0+5)); \
    DST[6]=(short)bfr(BVAL(SRC,RB,k0+6)); DST[7]=(short)bfr(BVAL(SRC,RB,k0+7)); }

// Self-sufficient builder: each block derives ALL constants from raw inputs in
// LDS (parallel reductions, no serial single-block prep, no dead Gram work),
// then computes its slice via MFMA. MODE 0: synthetic-grid x -> F-table (out=ws).
// MODE 1: x from x_t -> direct full-N output (fallback if ws too small).
template<int MODE>
__global__ __launch_bounds__(256, 2) void ml_build(
    const float* __restrict__ x_t,
    const float* __restrict__ W1, const float* __restrict__ b1,
    const float* __restrict__ Wih, const float* __restrict__ Whh,
    const float* __restrict__ b_ih, const float* __restrict__ b_hh,
    const float* __restrict__ g_x, const float* __restrict__ be_x,
    const float* __restrict__ g_h, const float* __restrict__ be_h,
    const float* __restrict__ g_c, const float* __restrict__ be_c,
    const float* __restrict__ Wo, const float* __restrict__ bo,
    float* out, int n)
{
    __shared__ __align__(16) float WA[1600];   // raw Wih layer-0
    __shared__ __align__(16) float Wc[1600];   // Wih layer-1: raw, then centered
    __shared__ __align__(16) float Vc[1600];   // Whh layer-1: raw, then centered
    __shared__ float w1s[HN], b1s[HN];
    __shared__ float lA[G4], lC[G4];
    __shared__ float cmr[2][HN][4];            // column-mean partials
    __shared__ float red[48], redm[2], stats[3];
    __shared__ float lAg[G4], lCg[G4], lK0[G4];
    __shared__ float lsg0[HN], lsb0[HN];
    __shared__ float lbo[1];
    __shared__ f32x4 LT[112];                  // colTab(80)+kTab(16)+kTab4(16)
    __shared__ __align__(16) unsigned short At[4][64 * 40];
    __shared__ __align__(16) unsigned short C0R[4][64][24];

    const int tid = threadIdx.x, wv = tid >> 6, l = tid & 63;

    // ---- A: stage weights (coalesced float4) ----
    {
        const f32x4* a0 = (const f32x4*)Wih;
        const f32x4* a1 = (const f32x4*)(Wih + 1600);
        const f32x4* a2 = (const f32x4*)(Whh + 1600);
        f32x4* dA = (f32x4*)WA; f32x4* dW = (f32x4*)Wc; f32x4* dV = (f32x4*)Vc;
        for (int i = tid; i < 400; i += 256) { dA[i] = a0[i]; dW[i] = a1[i]; dV[i] = a2[i]; }
        if (tid < HN) { w1s[tid] = W1[tid]; b1s[tid] = b1[tid]; }
    }
    __syncthreads();

    // ---- B1: column partial sums (raw)  ||  C1: A/C rows ----
    if (tid < 160) {
        int m = tid / 80, rem = tid % 80, col = rem % HN, part = rem / HN;
        const float* s = m ? Vc : Wc;
        float sum = 0.f;
        for (int r = part * 20; r < part * 20 + 20; ++r) sum += s[r * HN + col];
        cmr[m][col][part] = sum;
    }
    if (tid >= 160 && tid < 240) {
        int t80 = tid - 160;
        float Av = 0.f, Cv = 0.f;
        for (int k = 0; k < HN; ++k) {
            float w = WA[t80 * HN + k];
            Av = fmaf(w, w1s[k], Av); Cv = fmaf(w, b1s[k], Cv);
        }
        lA[t80] = Av; lC[t80] = Cv;
    }
    __syncthreads();

    // ---- cm finalize || A/C mean partials ----
    if (tid < 40) {
        int m = tid / HN, col = tid % HN;
        cmr[m][col][0] = (cmr[m][col][0] + cmr[m][col][1] + cmr[m][col][2] + cmr[m][col][3]) * (1.f / 80.f);
    }
    if (tid >= 64 && tid < 96) {
        int m = (tid - 64) / 16, i = (tid - 64) % 16;
        const float* s = m ? lC : lA;
        float sum = 0.f;
        for (int j = i * 5; j < i * 5 + 5; ++j) sum += s[j];
        red[tid - 64] = sum;
    }
    __syncthreads();

    // ---- mean finalize || center Wc/Vc in place ----
    if (tid < 2) { float s = 0.f; for (int i = 0; i < 16; ++i) s += red[tid * 16 + i]; redm[tid] = s * (1.f / 80.f); }
    for (int idx = tid; idx < 1600; idx += 256) {
        int col = idx % HN;
        Wc[idx] -= cmr[0][col][0];
        Vc[idx] -= cmr[1][col][0];
    }
    __syncthreads();

    const float am = redm[0], c_m = redm[1];
    // ---- central-moment partials (va, cov, vc) ----
    if (tid < 48) {
        int q = tid / 16, i = tid % 16;
        float s = 0.f;
        for (int j = i * 5; j < i * 5 + 5; ++j) {
            float ah = lA[j] - am, ch = lC[j] - c_m;
            s += (q == 0) ? ah * ah : (q == 1) ? ah * ch : ch * ch;
        }
        red[tid] = s;
    }
    __syncthreads();

    // ---- stats finalize || all derived constant tables ----
    if (tid < 3) { float s = 0.f; for (int i = 0; i < 16; ++i) s += red[tid * 16 + i]; stats[tid] = s * (1.f / 80.f); }
    if (tid < G4) {
        float sc0 = (tid >= 40 && tid < 60) ? (2.f * L2E) : (-L2E);
        lAg[tid] = (lA[tid] - am) * g_x[tid] * sc0;
        lCg[tid] = (lC[tid] - c_m) * g_x[tid] * sc0;
        lK0[tid] = (be_x[tid] + be_h[tid] + b_ih[tid] + b_hh[tid]) * sc0;
        // colTab entry tid = 16*tau + c
        int tau = tid >> 4, c = tid & 15;
        int g, u;
        if (tau < 4) { g = tau; u = c; }
        else         { g = c & 3; u = 16 + (c >> 2); }
        int row = g * 20 + u;
        float sc = (g == 2) ? (2.f * L2E) : (-L2E);
        float k1 = be_x[80 + row] + be_h[80 + row] + b_ih[80 + row] + b_hh[80 + row]
                 + ((g == 1) ? 1.f : 0.f);
        float aa = (g == 2) ? 1.f : 0.f;
        float bb = (g == 2) ? -2.f : 1.f;
        f32x4 e; e[0] = g_x[80 + row] * sc; e[1] = g_h[80 + row] * sc;
        e[2] = k1 * sc; e[3] = __uint_as_float(bfr(aa) | (bfr(bb) << 16));
        LT[tid] = e;
    }
    if (tid >= 96 && tid < 96 + HN) {
        int k = tid - 96;
        lsg0[k] = g_c[k] * (2.f * L2E);
        lsb0[k] = be_c[k] * (2.f * L2E);
    }
    if (tid >= 128 && tid < 144) {
        int c = tid - 128;
        f32x4 e; e[0] = g_c[HN + c] * (2.f * L2E); e[1] = be_c[HN + c] * (2.f * L2E);
        e[2] = Wo[c]; e[3] = 0.f;
        LT[80 + c] = e;
    }
    if (tid >= 160 && tid < 176) {
        int c = tid - 160, u = 16 + (c >> 2);
        f32x4 e; e[0] = g_c[HN + u] * (2.f * L2E); e[1] = be_c[HN + u] * (2.f * L2E);
        e[2] = Wo[u] * 0.25f; e[3] = 0.f;
        LT[96 + c] = e;
    }
    if (tid == 255) lbo[0] = bo[0];
    __syncthreads();

    // ---- E: B fragments per lane, straight from centered LDS weights ----
    const int c16 = l & 15, hi = l >> 4, q = c16 >> 2;
    const int k0 = hi * 8;
    const int rb0 = (0 * 20 + c16) * HN, rb1 = (1 * 20 + c16) * HN,
              rb2 = (2 * 20 + c16) * HN, rb3 = (3 * 20 + c16) * HN,
              rb4 = ((c16 & 3) * 20 + 16 + (c16 >> 2)) * HN;
    short8 B0, B1, B2, B3, B4, B5, B6, B7, B8, B9;
    MKB(B0, Wc, rb0) MKB(B1, Wc, rb1) MKB(B2, Wc, rb2) MKB(B3, Wc, rb3) MKB(B4, Wc, rb4)
    MKB(B5, Vc, rb0) MKB(B6, Vc, rb1) MKB(B7, Vc, rb2) MKB(B8, Vc, rb3) MKB(B9, Vc, rb4)

    // ---- F: layer 0 (closed form) -> At/C0R ----
    const int gi0 = blockIdx.x * 256 + tid;
    float x;
    if constexpr (MODE == 0) {
        x = (float)(gi0 - FT_N / 2) * (16.f / (float)FT_N);
    } else {
        x = (gi0 < n) ? x_t[gi0] : 0.f;
    }
    {
        const float* Ag = lAg;
        const float* Cg = lCg;
        const float* K0 = lK0;
        const float* sg0 = lsg0;
        const float* sb0 = lsb0;
        const float va = stats[0], cov = stats[1], vc = stats[2];
        const float rs0 = RSQ(fmaf(va * x, x, fmaf(2.f * cov, x, vc)) + EPSC);
        float mu = 0.f, m2 = 0.f;
        REP20(L0A)
        mu *= 0.05f;
        const float rsc = RSQ(fmaf(m2, 0.05f, -mu * mu) + EPSC);
        REP20(L0B)
        unsigned short* arow = &At[wv][l * 40];
        i32x4 aw0; aw0[0] = PKH(0,1); aw0[1] = PKH(2,3); aw0[2] = PKH(4,5); aw0[3] = PKH(6,7);
        i32x4 aw1; aw1[0] = PKH(8,9); aw1[1] = PKH(10,11); aw1[2] = PKH(12,13); aw1[3] = PKH(14,15);
        i32x4 aw2; aw2[0] = PKH(16,17); aw2[1] = PKH(18,19); aw2[2] = 0; aw2[3] = 0;
        i32x4 zz4; zz4[0] = 0; zz4[1] = 0; zz4[2] = 0; zz4[3] = 0;
        *(i32x4*)(arow + 0)  = aw0;
        *(i32x4*)(arow + 8)  = aw1;
        *(i32x4*)(arow + 16) = aw2;
        *(i32x4*)(arow + 24) = zz4;   // zero K-slots 24..31 (MFMA reads them)
        i32x4 cw0; cw0[0] = PKC(0,1); cw0[1] = PKC(2,3); cw0[2] = PKC(4,5); cw0[3] = PKC(6,7);
        i32x4 cw1; cw1[0] = PKC(8,9); cw1[1] = PKC(10,11); cw1[2] = PKC(12,13); cw1[3] = PKC(14,15);
        i32x2 cw2; cw2[0] = PKC(16,17); cw2[1] = PKC(18,19);
        unsigned short* crow = &C0R[wv][l][0];
        *(i32x4*)(crow + 0)  = cw0;
        *(i32x4*)(crow + 8)  = cw1;
        *(i32x2*)(crow + 16) = cw2;
    }
    __syncthreads();

    // ---- MFMA + lane-owns-unit epilogue (identical math to round 13) ----
    const f32x4 ct0 = LT[c16],      ct1 = LT[16 + c16], ct2 = LT[32 + c16],
                ct3 = LT[48 + c16], ct4 = LT[64 + c16];
    const f32x4 km = LT[80 + c16], k4 = LT[96 + c16];
    const u32 ab4 = __float_as_uint(ct4[3]);
    const float a4 = bfu(ab4 & 0xffffu), b4 = bfu(ab4 >> 16);
    const float bo_ = lbo[0];

    for (int af = 0; af < 4; ++af) {
        short8 a8 = *(const short8*)&At[wv][(af * 16 + c16) * 40 + hi * 8];
        f32x4 z4; z4[0] = 0.f; z4[1] = 0.f; z4[2] = 0.f; z4[3] = 0.f;
        f32x4 U0 = __builtin_amdgcn_mfma_f32_16x16x32_bf16(a8, B0, z4, 0, 0, 0);
        f32x4 U1 = __builtin_amdgcn_mfma_f32_16x16x32_bf16(a8, B1, z4, 0, 0, 0);
        f32x4 U2 = __builtin_amdgcn_mfma_f32_16x16x32_bf16(a8, B2, z4, 0, 0, 0);
        f32x4 U3 = __builtin_amdgcn_mfma_f32_16x16x32_bf16(a8, B3, z4, 0, 0, 0);
        f32x4 U4 = __builtin_amdgcn_mfma_f32_16x16x32_bf16(a8, B4, z4, 0, 0, 0);
        f32x4 V0 = __builtin_amdgcn_mfma_f32_16x16x32_bf16(a8, B5, z4, 0, 0, 0);
        f32x4 V1 = __builtin_amdgcn_mfma_f32_16x16x32_bf16(a8, B6, z4, 0, 0, 0);
        f32x4 V2 = __builtin_amdgcn_mfma_f32_16x16x32_bf16(a8, B7, z4, 0, 0, 0);
        f32x4 V3 = __builtin_amdgcn_mfma_f32_16x16x32_bf16(a8, B8, z4, 0, 0, 0);
        f32x4 V4 = __builtin_amdgcn_mfma_f32_16x16x32_bf16(a8, B9, z4, 0, 0, 0);

        f32x4 su4 = U0 * U0;
        su4 = __builtin_elementwise_fma(U1, U1, su4);
        su4 = __builtin_elementwise_fma(U2, U2, su4);
        su4 = __builtin_elementwise_fma(U3, U3, su4);
        su4 = __builtin_elementwise_fma(U4, U4, su4);
        f32x4 sv4 = V0 * V0;
        sv4 = __builtin_elementwise_fma(V1, V1, sv4);
        sv4 = __builtin_elementwise_fma(V2, V2, sv4);
        sv4 = __builtin_elementwise_fma(V3, V3, sv4);
        sv4 = __builtin_elementwise_fma(V4, V4, sv4);
        f32x4 rsu4, rsv4;
#define RSUR(r) { float s_ = su4[r]; RED16(s_); rsu4[r] = RSQ(fmaf(s_, 0.0125f, EPSC)); \
                  float t_ = sv4[r]; RED16(t_); rsv4[r] = RSQ(fmaf(t_, 0.0125f, EPSC)); }
        RSUR(0) RSUR(1) RSUR(2) RSUR(3)

        const int gibase = blockIdx.x * 256 + wv * 64 + af * 16;
#define EPI(r) { \
    float z0_ = fmaf(U0[r] * ct0[0], rsu4[r], fmaf(V0[r] * ct0[1], rsv4[r], ct0[2])); \
    float z1_ = fmaf(U1[r] * ct1[0], rsu4[r], fmaf(V1[r] * ct1[1], rsv4[r], ct1[2])); \
    float z2_ = fmaf(U2[r] * ct2[0], rsu4[r], fmaf(V2[r] * ct2[1], rsv4[r], ct2[2])); \
    float z3_ = fmaf(U3[r] * ct3[0], rsu4[r], fmaf(V3[r] * ct3[1], rsv4[r], ct3[2])); \
    float z4_ = fmaf(U4[r] * ct4[0], rsu4[r], fmaf(V4[r] * ct4[1], rsv4[r], ct4[2])); \
    float wi_ = RCP(1.f + EXP2(z0_)); \
    float wf_ = RCP(1.f + EXP2(z1_)); \
    float wg_ = fmaf(-2.f, RCP(1.f + EXP2(z2_)), 1.f); \
    float wo_ = RCP(1.f + EXP2(z3_)); \
    float w4_ = fmaf(b4, RCP(1.f + EXP2(z4_)), a4); \
    float wi4_ = DPPF(w4_, 0x00), wf4_ = DPPF(w4_, 0x55); \
    float wg4_ = DPPF(w4_, 0xAA), wo4_ = DPPF(w4_, 0xFF); \
    float c0m_ = bfu((u32)C0R[wv][af * 16 + hi * 4 + (r)][c16]); \
    float c0t_ = bfu((u32)C0R[wv][af * 16 + hi * 4 + (r)][16 + q]); \
    float c1m_ = fmaf(wf_, c0m_, wi_ * wg_); \
    float c1t_ = fmaf(wf4_, c0t_, wi4_ * wg4_); \
    float s1_ = fmaf(0.25f, c1t_, c1m_); RED16(s1_); \
    float s2_ = fmaf(c1t_ * 0.25f, c1t_, c1m_ * c1m_); RED16(s2_); \
    float mu_ = s1_ * 0.05f; \
    float rsc_ = RSQ(fmaf(s2_, 0.05f, -mu_ * mu_) + EPSC); \
    float tnm_ = TANH2(fmaf((c1m_ - mu_) * rsc_, km[0], km[1])); \
    float tnt_ = TANH2(fmaf((c1t_ - mu_) * rsc_, k4[0], k4[1])); \
    float o_ = fmaf(wo_ * tnm_, km[2], wo4_ * tnt_ * k4[2]); \
    RED16(o_); \
    if (c16 == (r)) { int gi_ = gibase + hi * 4 + (r); \
        if (gi_ < n) out[gi_] = o_ + bo_; } }
        EPI(0) EPI(1) EPI(2) EPI(3)
    }
}

// ---------------- final pass: out[i] = lerp(F-table, x[i]) -----------------
__global__ __launch_bounds__(256) void ml_apply(
    const float* __restrict__ x_t,
    const float* __restrict__ ftab,
    float* __restrict__ out, int n)
{
    const int g = blockIdx.x * 256 + threadIdx.x;
    const int base = g * 4;
    if (base + 4 <= n) {
        f32x4 xv = *(const f32x4*)(x_t + base);
        f32x4 ov;
#pragma unroll
        for (int j = 0; j < 4; ++j) {
            float xf = fmaf(xv[j], 2048.f, 16384.f);       // (x+8)*2048
            xf = fminf(fmaxf(xf, 0.f), (float)(FT_N - 2));
            float fl = floorf(xf);
            int idx = (int)fl;
            float fr = xf - fl;
            float a = ftab[idx], b = ftab[idx + 1];
            ov[j] = fmaf(fr, b - a, a);
        }
        *(f32x4*)(out + base) = ov;
    } else if (base < n) {
        for (int j = 0; j < n - base; ++j) {
            float xf = fmaf(x_t[base + j], 2048.f, 16384.f);
            xf = fminf(fmaxf(xf, 0.f), (float)(FT_N - 2));
            float fl = floorf(xf);
            int idx = (int)fl;
            float fr = xf - fl;
            float a = ftab[idx], b = ftab[idx + 1];
            out[base + j] = fmaf(fr, b - a, a);
        }
    }
}

extern "C" void kernel_launch(void* const* d_in, const int* in_sizes, int n_in,
                              void* d_out, int out_size, void* d_ws, size_t ws_size,
                              hipStream_t stream) {
    const float* x_t  = (const float*)d_in[0];
    const float* W1   = (const float*)d_in[1];
    const float* b1   = (const float*)d_in[2];
    const float* Wih  = (const float*)d_in[3];
    const float* Whh  = (const float*)d_in[4];
    const float* b_ih = (const float*)d_in[5];
    const float* b_hh = (const float*)d_in[6];
    const float* g_x  = (const float*)d_in[7];
    const float* be_x = (const float*)d_in[8];
    const float* g_h  = (const float*)d_in[9];
    const float* be_h = (const float*)d_in[10];
    const float* g_c  = (const float*)d_in[11];
    const float* be_c = (const float*)d_in[12];
    const float* Wo   = (const float*)d_in[13];
    const float* bo   = (const float*)d_in[14];
    float* out = (float*)d_out;
    float* ws  = (float*)d_ws;
    const int n = in_sizes[0];

    const size_t need = (size_t)FT_N * 4;
    if (ws_size >= need) {
        hipLaunchKernelGGL(ml_build<0>, dim3(FT_N / 256), dim3(256), 0, stream,
                           x_t, W1, b1, Wih, Whh, b_ih, b_hh, g_x, be_x, g_h, be_h,
                           g_c, be_c, Wo, bo, ws, FT_N);
        const int g4 = (n + 3) / 4;
        hipLaunchKernelGGL(ml_apply, dim3((g4 + 255) / 256), dim3(256), 0, stream,
                           x_t, ws, out, n);
    } else {
        const int blocks = (n + 255) / 256;
        hipLaunchKernelGGL(ml_build<1>, dim3(blocks), dim3(256), 0, stream,
                           x_t, W1, b1, Wih, Whh, b_ih, b_hh, g_x, be_x, g_h, be_h,
                           g_c, be_c, Wo, bo, out, n);
    }
}